// Round 9
// baseline (502.917 us; speedup 1.0000x reference)
//
#include <hip/hip_runtime.h>
#include <hip/hip_bf16.h>
#include <stdint.h>

// ---------- problem constants ----------
#define NTOK 8192   // B*T

typedef unsigned short u16;
typedef __attribute__((ext_vector_type(4))) float f32x4;
typedef __attribute__((ext_vector_type(8))) short s16x8;
typedef __attribute__((ext_vector_type(4))) short s16x4;
typedef __attribute__((ext_vector_type(8))) u16   u16x8;
typedef __attribute__((ext_vector_type(4))) u16   u16x4;
typedef __attribute__((ext_vector_type(4))) uint32_t u32x4;

__device__ __forceinline__ float fast_exp2(float x) {
    return __builtin_amdgcn_exp2f(x);
}
__device__ __forceinline__ u16 f2bf(float f) {
    uint32_t u = __float_as_uint(f);
    u = (u + 0x7FFFu + ((u >> 16) & 1u)) >> 16;   // RNE
    return (u16)u;
}
__device__ __forceinline__ float bf2f(u16 h) {
    return __uint_as_float(((uint32_t)h) << 16);
}
__device__ __forceinline__ void async_cp16(const void* g, void* l) {
    __builtin_amdgcn_global_load_lds(
        (const __attribute__((address_space(1))) void*)g,
        (__attribute__((address_space(3))) void*)l, 16, 0, 0);
}
__device__ __forceinline__ void wait_vm4()   { asm volatile("s_waitcnt vmcnt(4)" ::: "memory"); }
__device__ __forceinline__ void wait_vm0()   { asm volatile("s_waitcnt vmcnt(0)" ::: "memory"); }
__device__ __forceinline__ void wait_lgkm0() { asm volatile("s_waitcnt lgkmcnt(0)" ::: "memory"); }
__device__ __forceinline__ void raw_barrier(){ asm volatile("s_barrier" ::: "memory"); }

// XCD-aware tile remap (T1): dispatch order round-robins XCDs; give XCD k a
// CONTIGUOUS chunk of work tiles so same-XCD blocks share A-panels in its L2.
// Requires nwg % 8 == 0 (true for every grid below).
__device__ __forceinline__ void xcd_tile(int& bx, int& by) {
    int gx = gridDim.x;
    int nwg = gx * gridDim.y;
    int flat = blockIdx.y * gx + blockIdx.x;
    int swz = (flat & 7) * (nwg >> 3) + (flat >> 3);
    bx = swz % gx;
    by = swz / gx;
}

// ---------- all weight transposes in one launch: f32 [K][N] -> bf16 [N][K] ----------
struct TDesc { const float* s; u16* d; int K; int N; int tile0; };
struct TPack { TDesc t[8]; };

__global__ __launch_bounds__(256) void k_transpose_all(TPack p)
{
    __shared__ float tile[32][33];
    int bid = blockIdx.x;
    int i = 0;
    #pragma unroll
    for (int j = 1; j < 8; j++) if (bid >= p.t[j].tile0) i = j;
    const float* src = p.t[i].s;
    u16* dst = p.t[i].d;
    int K = p.t[i].K, N = p.t[i].N;
    int local = bid - p.t[i].tile0;
    int nx = N >> 5;
    int n0 = (local % nx) * 32, k0 = (local / nx) * 32;
    int tx = threadIdx.x, ty = threadIdx.y;      // block (32,8)
    #pragma unroll
    for (int r = 0; r < 32; r += 8)
        tile[ty + r][tx] = src[(size_t)(k0 + ty + r) * N + n0 + tx];
    __syncthreads();
    #pragma unroll
    for (int r = 0; r < 32; r += 8)
        dst[(size_t)(n0 + ty + r) * K + k0 + tx] = f2bf(tile[tx][ty + r]);
}

// ---------- f32 -> bf16 flat convert ----------
__global__ __launch_bounds__(256) void k_cvt(
    const float* __restrict__ in, u16* __restrict__ out)
{
    int i = (blockIdx.x * 256 + threadIdx.x) * 4;
    f32x4 v = *(const f32x4*)&in[i];
    u16x4 o;
    #pragma unroll
    for (int j = 0; j < 4; j++) o[j] = f2bf(v[j]);
    *(u16x4*)&out[i] = o;
}

// ---------- RMSNorm: f32 in, bf16 out ----------
template<int W>
__global__ __launch_bounds__(256) void k_rmsnorm(
    const float* __restrict__ x, const float* __restrict__ w, u16* __restrict__ out)
{
    constexpr int E = W / 256;
    int row = blockIdx.x, tid = threadIdx.x;
    const float* xr = x + (size_t)row * W;
    float v[E]; float ss = 0.f;
    #pragma unroll
    for (int i = 0; i < E; i++) { v[i] = xr[tid + i * 256]; ss += v[i] * v[i]; }
    #pragma unroll
    for (int m = 1; m < 64; m <<= 1) ss += __shfl_xor(ss, m, 64);
    __shared__ float red[4];
    if ((tid & 63) == 0) red[tid >> 6] = ss;
    __syncthreads();
    ss = red[0] + red[1] + red[2] + red[3];
    float scale = rsqrtf(ss / (float)W + 1e-6f);
    u16* orow = out + (size_t)row * W;
    #pragma unroll
    for (int i = 0; i < E; i++)
        orow[tid + i * 256] = f2bf(w[tid + i * 256] * (v[i] * scale));
}

// ---------- GEMM 128x128 tile, double-buffered pipelined K-loop ----------
// EPI: 0 = f32 store; 1 = bf16 store; 2 = gelu(tanh)+bf16; 3 = f32 + resid
template<int EPI>
__global__ __launch_bounds__(256) void k_gemm(
    const u16* __restrict__ A, int lda,
    const u16* __restrict__ Bt, int ldb,
    int M, int N, int K,
    float* __restrict__ outF, u16* __restrict__ outB,
    const float* __restrict__ resid)
{
    __shared__ __align__(16) u16 As[2][4096];
    __shared__ __align__(16) u16 Bs[2][4096];
    int tid = threadIdx.x;
    int w = tid >> 6, lane = tid & 63;
    int bx, by; xcd_tile(bx, by);
    int m0 = by * 128, n0 = bx * 128;
    int wm = w & 1, wn = w >> 1;
    int lr = lane & 15, lq = lane >> 4;

    f32x4 acc[4][4];
    #pragma unroll
    for (int i = 0; i < 4; i++)
        #pragma unroll
        for (int j = 0; j < 4; j++) acc[i][j] = (f32x4)(0.f);

    int ar = tid >> 2;
    int ac = (tid & 3) * 8;
    const u16* Ag = A  + (size_t)(m0 + ar) * lda + ac;
    const u16* Bg = Bt + (size_t)(n0 + ar) * ldb + ac;
    int lo = w * 512;

    auto stage = [&](int kt, int s) {
        const u16* a  = Ag + kt * 32;
        const u16* bp = Bg + kt * 32;
        async_cp16(a,                     &As[s][lo]);
        async_cp16(a + (size_t)64 * lda,  &As[s][lo + 2048]);
        async_cp16(bp,                    &Bs[s][lo]);
        async_cp16(bp + (size_t)64 * ldb, &Bs[s][lo + 2048]);
    };

    int nk = K >> 5;
    stage(0, 0);
    stage(1, 1);
    for (int k = 0; k < nk; k++) {
        if (k + 1 < nk) wait_vm4(); else wait_vm0();
        raw_barrier();
        int s = k & 1;
        s16x8 af[4], bfr[4];
        #pragma unroll
        for (int ms = 0; ms < 4; ms++)
            af[ms] = *reinterpret_cast<const s16x8*>(&As[s][(wm * 64 + ms * 16 + lr) * 32 + lq * 8]);
        #pragma unroll
        for (int ns = 0; ns < 4; ns++)
            bfr[ns] = *reinterpret_cast<const s16x8*>(&Bs[s][(wn * 64 + ns * 16 + lr) * 32 + lq * 8]);
        #pragma unroll
        for (int ms = 0; ms < 4; ms++)
            #pragma unroll
            for (int ns = 0; ns < 4; ns++)
                acc[ms][ns] = __builtin_amdgcn_mfma_f32_16x16x32_bf16(af[ms], bfr[ns], acc[ms][ns], 0, 0, 0);
        wait_lgkm0();
        raw_barrier();
        if (k + 2 < nk) stage(k + 2, s);
    }

    #pragma unroll
    for (int ms = 0; ms < 4; ms++) {
        #pragma unroll
        for (int ns = 0; ns < 4; ns++) {
            int col = n0 + wn * 64 + ns * 16 + lr;
            #pragma unroll
            for (int r = 0; r < 4; r++) {
                int row = m0 + wm * 64 + ms * 16 + lq * 4 + r;
                float v = acc[ms][ns][r];
                size_t idx = (size_t)row * N + col;
                if (EPI == 0) {
                    outF[idx] = v;
                } else if (EPI == 1) {
                    outB[idx] = f2bf(v);
                } else if (EPI == 2) {
                    // gelu(tanh) via exp2+rcp: 0.5v(1+tanh t) = v - v/(1+e^{2t})
                    float t = 0.7978845608028654f * (v + 0.044715f * v * v * v);
                    float e = fast_exp2(t * 2.8853900817779268f);
                    outB[idx] = f2bf(v - v * __builtin_amdgcn_rcpf(1.f + e));
                } else {
                    outF[idx] = v + resid[idx];
                }
            }
        }
    }
}

// ---------- GEMM 64x64 tile (kept for the small weight-fuse GEMM) ----------
template<int EPI>
__global__ __launch_bounds__(256) void k_gemm64(
    const u16* __restrict__ A, int lda,
    const u16* __restrict__ Bt, int ldb,
    int M, int N, int K,
    float* __restrict__ outF, u16* __restrict__ outB)
{
    __shared__ __align__(16) u16 As[2][4096];   // [kc2][64 rows][32 u16]
    __shared__ __align__(16) u16 Bs[2][4096];
    int tid = threadIdx.x;
    int w = tid >> 6, lane = tid & 63;
    int bx, by; xcd_tile(bx, by);
    int m0 = by * 64, n0 = bx * 64;
    int wm = w & 1, wn = w >> 1;
    int lr = lane & 15, lq = lane >> 4;

    f32x4 acc[2][2];
    #pragma unroll
    for (int i = 0; i < 2; i++)
        #pragma unroll
        for (int j = 0; j < 2; j++) acc[i][j] = (f32x4)(0.f);

    int srow = tid >> 2;            // 0..63
    int sq   = tid & 3;             // 16B quarter within 32-u16 chunk
    const u16* Ag = A  + (size_t)(m0 + srow) * lda + sq * 8;
    const u16* Bg = Bt + (size_t)(n0 + srow) * ldb + sq * 8;
    int lo = srow * 32 + sq * 8;

    auto stage = [&](int kt, int s) {
        const u16* a  = Ag + kt * 64;
        const u16* bp = Bg + kt * 64;
        async_cp16(a,       &As[s][lo]);
        async_cp16(a + 32,  &As[s][2048 + lo]);
        async_cp16(bp,      &Bs[s][lo]);
        async_cp16(bp + 32, &Bs[s][2048 + lo]);
    };

    int nk = K >> 6;
    stage(0, 0);
    stage(1, 1);
    for (int k = 0; k < nk; k++) {
        if (k + 1 < nk) wait_vm4(); else wait_vm0();
        raw_barrier();
        int s = k & 1;
        s16x8 af[2][2], bfr[2][2];
        #pragma unroll
        for (int kc = 0; kc < 2; kc++) {
            #pragma unroll
            for (int ms = 0; ms < 2; ms++)
                af[ms][kc] = *reinterpret_cast<const s16x8*>(
                    &As[s][kc * 2048 + (wm * 32 + ms * 16 + lr) * 32 + lq * 8]);
            #pragma unroll
            for (int ns = 0; ns < 2; ns++)
                bfr[ns][kc] = *reinterpret_cast<const s16x8*>(
                    &Bs[s][kc * 2048 + (wn * 32 + ns * 16 + lr) * 32 + lq * 8]);
        }
        #pragma unroll
        for (int kc = 0; kc < 2; kc++)
            #pragma unroll
            for (int ms = 0; ms < 2; ms++)
                #pragma unroll
                for (int ns = 0; ns < 2; ns++)
                    acc[ms][ns] = __builtin_amdgcn_mfma_f32_16x16x32_bf16(
                        af[ms][kc], bfr[ns][kc], acc[ms][ns], 0, 0, 0);
        wait_lgkm0();
        raw_barrier();
        if (k + 2 < nk) stage(k + 2, s);
    }

    #pragma unroll
    for (int ms = 0; ms < 2; ms++) {
        #pragma unroll
        for (int ns = 0; ns < 2; ns++) {
            int col = n0 + wn * 32 + ns * 16 + lr;
            #pragma unroll
            for (int r = 0; r < 4; r++) {
                int row = m0 + wm * 32 + ms * 16 + lq * 4 + r;
                float v = acc[ms][ns][r];
                size_t idx = (size_t)row * N + col;
                if (EPI == 0) outF[idx] = v;
                else          outB[idx] = f2bf(v);
            }
        }
    }
}

// ---------- RoPE (x8 vectorized) ----------
__global__ __launch_bounds__(256) void k_rope(
    const u16* __restrict__ q, const u16* __restrict__ kv,
    const float* __restrict__ cosb, const float* __restrict__ sinb,
    u16* __restrict__ q_r, u16* __restrict__ k_r)
{
    const float QS = 0.125f * 1.4426950408889634f;
    int idx = blockIdx.x * 256 + threadIdx.x;    // B*T*H*8 threads
    int g = idx & 7;
    int h = (idx >> 3) & 15;
    int t = (idx >> 7) & 2047;
    int b = idx >> 18;
    size_t qsrc = ((size_t)((b * 2048 + t) * 16 + h)) * 64 + g * 8;
    size_t ksrc = ((size_t)((b * 2048 + t) * 16 + h)) * 128 + g * 8;
    u16x8 qa = *(const u16x8*)&q[qsrc];
    u16x8 ka = *(const u16x8*)&kv[ksrc];
    u16x8 qo, ko;
    if (g < 4) {
        int pd = ((g ^ 2) - g) * 8;
        u16x8 qp = *(const u16x8*)&q[qsrc + pd];
        u16x8 kp = *(const u16x8*)&kv[ksrc + pd];
        float sgn = (g < 2) ? -1.f : 1.f;
        const float* cp = &cosb[t * 32 + g * 8];
        const float* sp = &sinb[t * 32 + g * 8];
        #pragma unroll
        for (int j = 0; j < 8; j++) {
            float c = cp[j], s = sp[j];
            qo[j] = f2bf((bf2f(qa[j]) * c + sgn * bf2f(qp[j]) * s) * QS);
            ko[j] = f2bf(bf2f(ka[j]) * c + sgn * bf2f(kp[j]) * s);
        }
    } else {
        #pragma unroll
        for (int j = 0; j < 8; j++) {
            qo[j] = f2bf(bf2f(qa[j]) * QS);
            ko[j] = ka[j];
        }
    }
    size_t dst = ((size_t)(b * 16 + h) * 2048 + t) * 64 + g * 8;
    *(u16x8*)&q_r[dst] = qo;
    *(u16x8*)&k_r[dst] = ko;
}

// ---------- V transpose: kv [B,T,H,128] (v half) -> v_t [B,H,64,T] ----------
__global__ __launch_bounds__(256) void k_vtrans(
    const u16* __restrict__ kv, u16* __restrict__ v_t)
{
    __shared__ u16 tile[64][72];
    int bh = blockIdx.y;
    int b = bh >> 4, h = bh & 15;
    int t0 = blockIdx.x * 64;
    int tid = threadIdx.x;
    int r = tid >> 2;
    int c4 = (tid & 3) * 16;
    const u16* src = kv + ((size_t)((b * 2048 + t0 + r) * 16 + h)) * 128 + 64;
    #pragma unroll
    for (int j = 0; j < 16; j += 8)
        *(u16x8*)&tile[r][c4 + j] = *(const u16x8*)&src[c4 + j];
    __syncthreads();
    int dd = tid >> 2;
    u16* dst = v_t + ((size_t)bh * 64 + dd) * 2048 + t0;
    #pragma unroll
    for (int j0 = 0; j0 < 16; j0 += 8) {
        u16x8 vv;
        #pragma unroll
        for (int j = 0; j < 8; j++) vv[j] = tile[c4 + j0 + j][dd];
        *(u16x8*)&dst[c4 + j0] = vv;
    }
}

// ---------- flash attention v9 (verified 97us) ----------
// Keeps: XCD-partition remap (FETCH 139->41MB), pinned-zero C-operand, ones-MFMA
// row-sum, cvt_pk packing, 2-bit swizzle + dual ds_read_b64 V path,
// advancing-pointer staging, literal-offset 2x unroll, setprio, v_rcp epilogue.
// LDS analysis (r7): K b128 reads = 8 acc/bank (1KB minimum), V b64 = 4/bank
// (512B minimum) -> conflict-free; SQ_LDS_BANK_CONFLICT=2^23 is the inherent
// multi-phase cycle count of wide reads, not serialization. Parked.
__global__ __launch_bounds__(256) void k_attn(
    const u16* __restrict__ q_r, const u16* __restrict__ k_r,
    const u16* __restrict__ v_t, u16* __restrict__ ctx)
{
    __shared__ __align__(16) u16 Ks[2][4096];
    __shared__ __align__(16) u16 Vs[2][4096];
    int tid = threadIdx.x, w = tid >> 6, lane = tid & 63;
    // XCD-partition remap (8 XCDs, grid 1024 = 8 xcd * 8 bh * 16 xb)
    int flat = blockIdx.x;
    int xcd = flat & 7;
    int idx = flat >> 3;
    int bh  = xcd * 8 + (idx & 7);
    int xb  = idx >> 3;                         // 0..15
    int b = bh >> 4, h = bh & 15;
    int q0 = xb * 128 + w * 32;
    const u16* Qp = q_r + (size_t)bh * 2048 * 64;
    const u16* Kp = k_r + (size_t)bh * 2048 * 64;
    const u16* Vp = v_t + (size_t)bh * 64 * 2048;
    int lr = lane & 15, lq = lane >> 4;
    int swz = (lr >> 1) & 3;                    // 2-bit read-side chunk16 XOR

    s16x8 qf[2][2];
    #pragma unroll
    for (int qc = 0; qc < 2; qc++)
        #pragma unroll
        for (int kf = 0; kf < 2; kf++)
            qf[qc][kf] = *(const s16x8*)&Qp[(size_t)(q0 + qc * 16 + lr) * 64 + kf * 32 + lq * 8];

    // bf16 1.0 fragment for the ones-MFMA row-sum
    s16x8 ones;
    #pragma unroll
    for (int j = 0; j < 8; j++) ones[j] = (short)0x3F80;

    // pinned zero quad for QK accumulator C-operand
    f32x4 fz = (f32x4)(0.f);
    asm("" : "+v"(fz));

    // staging: pre-swizzled global source, linear LDS dest (2-bit swizzle).
    int schunk = ((lane & 3) ^ ((lane >> 3) & 3)) * 8;
    const u16* gp;
    u16 *lp0, *lp1;
    size_t grow;
    int gAdv;
    if (w < 2) {
        gp = Kp + (size_t)(lane >> 2) * 64 + w * 32 + schunk;
        lp0 = &Ks[0][w * 2048]; lp1 = &Ks[1][w * 2048];
        grow = 16 * 64;  gAdv = 64 * 64;
    } else {
        gp = Vp + (size_t)(lane >> 2) * 2048 + (w - 2) * 32 + schunk;
        lp0 = &Vs[0][(w - 2) * 2048]; lp1 = &Vs[1][(w - 2) * 2048];
        grow = 16 * 2048; gAdv = 64;
    }
    auto stageP = [&](u16* lp) {
        #pragma unroll
        for (int g = 0; g < 4; g++)
            async_cp16(gp + g * grow, lp + g * 512);
        gp += gAdv;
    };

    f32x4 o[2][4];
    #pragma unroll
    for (int qt = 0; qt < 2; qt++)
        #pragma unroll
        for (int ds = 0; ds < 4; ds++) o[qt][ds] = (f32x4)(0.f);
    f32x4 lacc0 = (f32x4)(0.f), lacc1 = (f32x4)(0.f);

#define ATTN_BODY(S)                                                           \
  {                                                                            \
    f32x4 sc[2][4];                                                            \
    __builtin_amdgcn_s_setprio(1);                                             \
    _Pragma("unroll")                                                          \
    for (int ns = 0; ns < 4; ns++) {                                           \
      int ko = (ns * 16 + lr) * 32 + ((lq ^ swz) * 8);                         \
      s16x8 a0 = *(const s16x8*)&Ks[S][ko];                                    \
      s16x8 a1 = *(const s16x8*)&Ks[S][2048 + ko];                             \
      _Pragma("unroll")                                                        \
      for (int qc = 0; qc < 2; qc++) {                                         \
        f32x4 t;                                                               \
        t = __builtin_amdgcn_mfma_f32_16x16x32_bf16(a0, qf[qc][0], fz, 0, 0, 0);\
        t = __builtin_amdgcn_mfma_f32_16x16x32_bf16(a1, qf[qc][1], t, 0, 0, 0);\
        sc[qc][ns] = t;                                                        \
      }                                                                        \
    }                                                                          \
    __builtin_amdgcn_s_setprio(0);                                             \
    _Pragma("unroll")                                                          \
    for (int kf = 0; kf < 2; kf++) {                                           \
      u32x4 w0, w1;                                                            \
      _Pragma("unroll")                                                        \
      for (int j = 0; j < 4; j++) {                                            \
        int ns = kf * 2 + (j >> 1);                                            \
        int r0 = (j & 1) * 2;                                                  \
        float ea = fast_exp2(sc[0][ns][r0]);                                   \
        float eb = fast_exp2(sc[0][ns][r0 + 1]);                               \
        float ec = fast_exp2(sc[1][ns][r0]);                                   \
        float ed = fast_exp2(sc[1][ns][r0 + 1]);                               \
        uint32_t t0, t1;                                                       \
        asm("v_cvt_pk_bf16_f32 %0, %1, %2" : "=v"(t0) : "v"(ea), "v"(eb));     \
        asm("v_cvt_pk_bf16_f32 %0, %1, %2" : "=v"(t1) : "v"(ec), "v"(ed));     \
        w0[j] = t0; w1[j] = t1;                                                \
      }                                                                        \
      s16x8 pk0 = __builtin_bit_cast(s16x8, w0);                               \
      s16x8 pk1 = __builtin_bit_cast(s16x8, w1);                               \
      __builtin_amdgcn_s_setprio(1);                                           \
      lacc0 = __builtin_amdgcn_mfma_f32_16x16x32_bf16(pk0, ones, lacc0, 0,0,0);\
      lacc1 = __builtin_amdgcn_mfma_f32_16x16x32_bf16(pk1, ones, lacc1, 0,0,0);\
      _Pragma("unroll")                                                        \
      for (int ds = 0; ds < 4; ds++) {                                         \
        int vbase = kf * 2048 + (ds * 16 + lr) * 32 + (lq & 1) * 4;            \
        s16x4 vlo = *(const s16x4*)&Vs[S][vbase + (((lq >> 1)    ) ^ swz) * 8];\
        s16x4 vhi = *(const s16x4*)&Vs[S][vbase + (((lq >> 1) | 2) ^ swz) * 8];\
        s16x8 vf = __builtin_shufflevector(vlo, vhi, 0, 1, 2, 3, 4, 5, 6, 7);  \
        o[0][ds] = __builtin_amdgcn_mfma_f32_16x16x32_bf16(pk0, vf, o[0][ds], 0, 0, 0);\
        o[1][ds] = __builtin_amdgcn_mfma_f32_16x16x32_bf16(pk1, vf, o[1][ds], 0, 0, 0);\
      }                                                                        \
      __builtin_amdgcn_s_setprio(0);                                           \
    }                                                                          \
  }

    stageP(lp0);   // tile 0 -> buf0
    stageP(lp1);   // tile 1 -> buf1
    for (int k2 = 0; k2 < 15; k2++) {
        wait_vm4(); raw_barrier();
        ATTN_BODY(0)
        wait_lgkm0(); raw_barrier();
        stageP(lp0);
        wait_vm4(); raw_barrier();
        ATTN_BODY(1)
        wait_lgkm0(); raw_barrier();
        stageP(lp1);
    }
    wait_vm4(); raw_barrier();
    ATTN_BODY(0)
    wait_vm0(); raw_barrier();
    ATTN_BODY(1)
#undef ATTN_BODY

    #pragma unroll
    for (int qt = 0; qt < 2; qt++) {
        f32x4 lv = qt ? lacc1 : lacc0;
        float li[4];
        #pragma unroll
        for (int r = 0; r < 4; r++) li[r] = __builtin_amdgcn_rcpf(lv[r]);
        #pragma unroll
        for (int ds = 0; ds < 4; ds++)
            #pragma unroll
            for (int r = 0; r < 4; r++) {
                int tq = q0 + qt * 16 + lq * 4 + r;
                float v = o[qt][ds][r] * li[r];
                ctx[((size_t)(b * 2048) + tq) * 1024 + h * 64 + ds * 16 + lr] = f2bf(v);
            }
    }
}

// ---------- host ----------
extern "C" void kernel_launch(void* const* d_in, const int* in_sizes, int n_in,
                              void* d_out, int out_size, void* d_ws, size_t ws_size,
                              hipStream_t stream) {
    (void)in_sizes; (void)n_in; (void)out_size; (void)ws_size;
    const float* x     = (const float*)d_in[0];
    const float* ln1   = (const float*)d_in[1];
    const float* alnw  = (const float*)d_in[2];
    const float* qkv_a = (const float*)d_in[3];
    const float* q_b   = (const float*)d_in[4];
    const float* kv_b  = (const float*)d_in[5];
    const float* o_a   = (const float*)d_in[6];
    const float* o_b   = (const float*)d_in[7];
    const float* ln2   = (const float*)d_in[8];
    const float* in_a  = (const float*)d_in[9];
    const float* in_b  = (const float*)d_in[10];
    const float* out_a = (const float*)d_in[11];
    const float* out_b = (const float*)d_in[12];
    const float* cosb  = (const float*)d_in[13];
    const float* sinb  = (const float*)d_in[14];
    float* out = (float*)d_out;
    char* ws = (char*)d_ws;

    // ---- weights bf16 [0, 15728640) ----
    u16* wqkv = (u16*)ws;              // 768x1024
    u16* wq   = wqkv + 786432;         // 1024x512
    u16* wkv  = wq   + 524288;         // 2048x256
    u16* wob  = wkv  + 524288;         // 1024x512 (o_b^T)
    u16* wia  = wob  + 524288;         // 384x1024
    u16* wib  = wia  + 393216;         // 4096x384
    u16* woa2 = wib  + 1572864;        // 384x4096 (out_a^T)
    u16* wob2 = woa2 + 1572864;        // 1024x384
    u16* woan = wob2 + 393216;         // 1024x512 (o_a cast)
    u16* woab = woan + 524288;         // 1024x1024 fused (o_a@o_b)^T

    // ---- activations, base G = ws + 15728640 ----
    char* G = ws + 15728640;
    u16*  hbuf  = (u16*)(G + 0);              // 16.8 MB [rms1 -> qkv]
    float* lat_raw = (float*)(G + 16777216);  // 25.2 MB [qkv -> rms768]
    u16*  lat   = (u16*)(G + 41943040);       // 12.6 MB [rms768 -> q,kv]
    u16*  qbuf  = (u16*)(G + 54525952);       // 16.8 MB [q -> rope]
    u16*  kvbuf = (u16*)(G + 71303168);       // 33.6 MB [kv -> rope,vtrans]
    u16*  q_r   = (u16*)(G + 0);              // reuse hbuf      [rope -> attn]
    u16*  k_r   = (u16*)(G + 16777216);       // reuse lat_raw   [rope -> attn]
    u16*  v_t   = (u16*)(G + 33554432);       // lat_raw tail+lat [vtrans -> attn]
    u16*  ctx   = (u16*)(G + 54525952);       // reuse qbuf      [attn -> o-gemm]
    float* x2   = (float*)(G + 0);            // 33.6 MB, reuse q_r/k_r [o -> final]
    u16*  h2    = (u16*)(G + 33554432);       // reuse v_t       [rms2 -> in_a]
    u16*  t1    = (u16*)(G + 50331648);       // 6.3 MB          [in_a -> in_b]
    u16*  t2    = (u16*)(G + 56623104);       // 64 MB           [in_b -> out_a]
    u16*  t3    = (u16*)(G + 50331648);       // reuse t1        [out_a -> out_b]

    TPack tp;
    tp.t[0] = { qkv_a, wqkv, 1024, 768,  0 };
    tp.t[1] = { q_b,   wq,   512,  1024, 768 };
    tp.t[2] = { kv_b,  wkv,  256,  2048, 1280 };
    tp.t[3] = { o_b,   wob,  512,  1024, 1792 };
    tp.t[4] = { in_a,  wia,  1024, 384,  2304 };
    tp.t[5] = { in_b,  wib,  384,  4096, 2688 };
    tp.t[6] = { out_a, woa2, 4096, 384,  4224 };
    tp.t[7] = { out_b, wob2, 384,  1024, 5760 };
    k_transpose_all<<<6144, dim3(32, 8), 0, stream>>>(tp);
    k_cvt<<<512, 256, 0, stream>>>(o_a, woan);
    // fused o-weight: W^T = o_b^T @ o_a  (bf16), [1024][1024]
    k_gemm64<1><<<dim3(16, 16), 256, 0, stream>>>(wob, 512, woan, 512, 1024, 1024, 512, nullptr, woab);

    k_rmsnorm<1024><<<NTOK, 256, 0, stream>>>(x, ln1, hbuf);
    // qkv: 128-tile (was 64-tile): grid 6x64=384 blocks
    k_gemm<0><<<dim3(6, 64), 256, 0, stream>>>(hbuf, 1024, wqkv, 1024, NTOK, 768, 1024, lat_raw, nullptr, nullptr);
    k_rmsnorm<768><<<NTOK, 256, 0, stream>>>(lat_raw, alnw, lat);
    k_gemm<1><<<dim3(8, 64),  256, 0, stream>>>(lat,       768, wq,  512, NTOK, 1024, 512, nullptr, qbuf,  nullptr);
    k_gemm<1><<<dim3(16, 64), 256, 0, stream>>>(lat + 512, 768, wkv, 256, NTOK, 2048, 256, nullptr, kvbuf, nullptr);
    k_rope<<<4096, 256, 0, stream>>>(qbuf, kvbuf, cosb, sinb, q_r, k_r);
    k_vtrans<<<dim3(32, 64), 256, 0, stream>>>(kvbuf, v_t);
    k_attn<<<1024, 256, 0, stream>>>(q_r, k_r, v_t, ctx);
    // attn_out + residual in one GEMM via fused weight
    k_gemm<3><<<dim3(8, 64), 256, 0, stream>>>(ctx, 1024, woab, 1024, NTOK, 1024, 1024, x2, nullptr, x);
    k_rmsnorm<1024><<<NTOK, 256, 0, stream>>>(x2, ln2, h2);
    // ffn in_a: 128-tile: grid 3x64=192 blocks
    k_gemm<1><<<dim3(3, 64), 256, 0, stream>>>(h2, 1024, wia, 1024, NTOK, 384, 1024, nullptr, t1, nullptr);
    k_gemm<2><<<dim3(32, 64), 256, 0, stream>>>(t1, 384, wib, 384, NTOK, 4096, 384, nullptr, t2, nullptr);
    // ffn out_a: 128-tile, K=4096 deep: grid 3x64=192 blocks
    k_gemm<1><<<dim3(3, 64), 256, 0, stream>>>(t2, 4096, woa2, 4096, NTOK, 384, 4096, nullptr, t3, nullptr);
    k_gemm<3><<<dim3(8, 64), 256, 0, stream>>>(t3, 384, wob2, 384, NTOK, 1024, 384, out, nullptr, x2);
}

// Round 11
// 489.151 us; speedup vs baseline: 1.0281x; 1.0281x over previous
//
#include <hip/hip_runtime.h>
#include <hip/hip_bf16.h>
#include <stdint.h>

// ---------- problem constants ----------
#define NTOK 8192   // B*T

typedef unsigned short u16;
typedef __attribute__((ext_vector_type(4))) float f32x4;
typedef __attribute__((ext_vector_type(8))) short s16x8;
typedef __attribute__((ext_vector_type(4))) short s16x4;
typedef __attribute__((ext_vector_type(8))) u16   u16x8;
typedef __attribute__((ext_vector_type(4))) u16   u16x4;
typedef __attribute__((ext_vector_type(4))) uint32_t u32x4;

__device__ __forceinline__ float fast_exp2(float x) {
    return __builtin_amdgcn_exp2f(x);
}
__device__ __forceinline__ u16 f2bf(float f) {
    uint32_t u = __float_as_uint(f);
    u = (u + 0x7FFFu + ((u >> 16) & 1u)) >> 16;   // RNE
    return (u16)u;
}
__device__ __forceinline__ float bf2f(u16 h) {
    return __uint_as_float(((uint32_t)h) << 16);
}
__device__ __forceinline__ void async_cp16(const void* g, void* l) {
    __builtin_amdgcn_global_load_lds(
        (const __attribute__((address_space(1))) void*)g,
        (__attribute__((address_space(3))) void*)l, 16, 0, 0);
}
__device__ __forceinline__ void wait_vm4()   { asm volatile("s_waitcnt vmcnt(4)" ::: "memory"); }
__device__ __forceinline__ void wait_vm3()   { asm volatile("s_waitcnt vmcnt(3)" ::: "memory"); }
__device__ __forceinline__ void wait_vm0()   { asm volatile("s_waitcnt vmcnt(0)" ::: "memory"); }
__device__ __forceinline__ void wait_lgkm0() { asm volatile("s_waitcnt lgkmcnt(0)" ::: "memory"); }
__device__ __forceinline__ void raw_barrier(){ asm volatile("s_barrier" ::: "memory"); }

// XCD-aware tile remap (T1): dispatch order round-robins XCDs; give XCD k a
// CONTIGUOUS chunk of work tiles so same-XCD blocks share A-panels in its L2.
// Requires nwg % 8 == 0 (true for every grid below).
__device__ __forceinline__ void xcd_tile(int& bx, int& by) {
    int gx = gridDim.x;
    int nwg = gx * gridDim.y;
    int flat = blockIdx.y * gx + blockIdx.x;
    int swz = (flat & 7) * (nwg >> 3) + (flat >> 3);
    bx = swz % gx;
    by = swz / gx;
}

// ---------- all weight transposes in one launch: f32 [K][N] -> bf16 [N][K] ----------
struct TDesc { const float* s; u16* d; int K; int N; int tile0; };
struct TPack { TDesc t[8]; };

__global__ __launch_bounds__(256) void k_transpose_all(TPack p)
{
    __shared__ float tile[32][33];
    int bid = blockIdx.x;
    int i = 0;
    #pragma unroll
    for (int j = 1; j < 8; j++) if (bid >= p.t[j].tile0) i = j;
    const float* src = p.t[i].s;
    u16* dst = p.t[i].d;
    int K = p.t[i].K, N = p.t[i].N;
    int local = bid - p.t[i].tile0;
    int nx = N >> 5;
    int n0 = (local % nx) * 32, k0 = (local / nx) * 32;
    int tx = threadIdx.x, ty = threadIdx.y;      // block (32,8)
    #pragma unroll
    for (int r = 0; r < 32; r += 8)
        tile[ty + r][tx] = src[(size_t)(k0 + ty + r) * N + n0 + tx];
    __syncthreads();
    #pragma unroll
    for (int r = 0; r < 32; r += 8)
        dst[(size_t)(n0 + ty + r) * K + k0 + tx] = f2bf(tile[tx][ty + r]);
}

// ---------- f32 -> bf16 flat convert ----------
__global__ __launch_bounds__(256) void k_cvt(
    const float* __restrict__ in, u16* __restrict__ out)
{
    int i = (blockIdx.x * 256 + threadIdx.x) * 4;
    f32x4 v = *(const f32x4*)&in[i];
    u16x4 o;
    #pragma unroll
    for (int j = 0; j < 4; j++) o[j] = f2bf(v[j]);
    *(u16x4*)&out[i] = o;
}

// ---------- RMSNorm: f32 in, bf16 out ----------
template<int W>
__global__ __launch_bounds__(256) void k_rmsnorm(
    const float* __restrict__ x, const float* __restrict__ w, u16* __restrict__ out)
{
    constexpr int E = W / 256;
    int row = blockIdx.x, tid = threadIdx.x;
    const float* xr = x + (size_t)row * W;
    float v[E]; float ss = 0.f;
    #pragma unroll
    for (int i = 0; i < E; i++) { v[i] = xr[tid + i * 256]; ss += v[i] * v[i]; }
    #pragma unroll
    for (int m = 1; m < 64; m <<= 1) ss += __shfl_xor(ss, m, 64);
    __shared__ float red[4];
    if ((tid & 63) == 0) red[tid >> 6] = ss;
    __syncthreads();
    ss = red[0] + red[1] + red[2] + red[3];
    float scale = rsqrtf(ss / (float)W + 1e-6f);
    u16* orow = out + (size_t)row * W;
    #pragma unroll
    for (int i = 0; i < E; i++)
        orow[tid + i * 256] = f2bf(w[tid + i * 256] * (v[i] * scale));
}

// ---------- GEMM 128x128 tile, double-buffered pipelined K-loop ----------
// EPI: 0 = f32 store; 1 = bf16 store; 2 = gelu(tanh)+bf16; 3 = f32 + resid
template<int EPI>
__global__ __launch_bounds__(256) void k_gemm(
    const u16* __restrict__ A, int lda,
    const u16* __restrict__ Bt, int ldb,
    int M, int N, int K,
    float* __restrict__ outF, u16* __restrict__ outB,
    const float* __restrict__ resid)
{
    __shared__ __align__(16) u16 As[2][4096];
    __shared__ __align__(16) u16 Bs[2][4096];
    int tid = threadIdx.x;
    int w = tid >> 6, lane = tid & 63;
    int bx, by; xcd_tile(bx, by);
    int m0 = by * 128, n0 = bx * 128;
    int wm = w & 1, wn = w >> 1;
    int lr = lane & 15, lq = lane >> 4;

    f32x4 acc[4][4];
    #pragma unroll
    for (int i = 0; i < 4; i++)
        #pragma unroll
        for (int j = 0; j < 4; j++) acc[i][j] = (f32x4)(0.f);

    int ar = tid >> 2;
    int ac = (tid & 3) * 8;
    const u16* Ag = A  + (size_t)(m0 + ar) * lda + ac;
    const u16* Bg = Bt + (size_t)(n0 + ar) * ldb + ac;
    int lo = w * 512;

    auto stage = [&](int kt, int s) {
        const u16* a  = Ag + kt * 32;
        const u16* bp = Bg + kt * 32;
        async_cp16(a,                     &As[s][lo]);
        async_cp16(a + (size_t)64 * lda,  &As[s][lo + 2048]);
        async_cp16(bp,                    &Bs[s][lo]);
        async_cp16(bp + (size_t)64 * ldb, &Bs[s][lo + 2048]);
    };

    int nk = K >> 5;
    stage(0, 0);
    stage(1, 1);
    for (int k = 0; k < nk; k++) {
        if (k + 1 < nk) wait_vm4(); else wait_vm0();
        raw_barrier();
        int s = k & 1;
        s16x8 af[4], bfr[4];
        #pragma unroll
        for (int ms = 0; ms < 4; ms++)
            af[ms] = *reinterpret_cast<const s16x8*>(&As[s][(wm * 64 + ms * 16 + lr) * 32 + lq * 8]);
        #pragma unroll
        for (int ns = 0; ns < 4; ns++)
            bfr[ns] = *reinterpret_cast<const s16x8*>(&Bs[s][(wn * 64 + ns * 16 + lr) * 32 + lq * 8]);
        #pragma unroll
        for (int ms = 0; ms < 4; ms++)
            #pragma unroll
            for (int ns = 0; ns < 4; ns++)
                acc[ms][ns] = __builtin_amdgcn_mfma_f32_16x16x32_bf16(af[ms], bfr[ns], acc[ms][ns], 0, 0, 0);
        wait_lgkm0();
        raw_barrier();
        if (k + 2 < nk) stage(k + 2, s);
    }

    #pragma unroll
    for (int ms = 0; ms < 4; ms++) {
        #pragma unroll
        for (int ns = 0; ns < 4; ns++) {
            int col = n0 + wn * 64 + ns * 16 + lr;
            #pragma unroll
            for (int r = 0; r < 4; r++) {
                int row = m0 + wm * 64 + ms * 16 + lq * 4 + r;
                float v = acc[ms][ns][r];
                size_t idx = (size_t)row * N + col;
                if (EPI == 0) {
                    outF[idx] = v;
                } else if (EPI == 1) {
                    outB[idx] = f2bf(v);
                } else if (EPI == 2) {
                    // gelu(tanh) via exp2+rcp: 0.5v(1+tanh t) = v - v/(1+e^{2t})
                    float t = 0.7978845608028654f * (v + 0.044715f * v * v * v);
                    float e = fast_exp2(t * 2.8853900817779268f);
                    outB[idx] = f2bf(v - v * __builtin_amdgcn_rcpf(1.f + e));
                } else {
                    outF[idx] = v + resid[idx];
                }
            }
        }
    }
}

// ---------- GEMM 128x64 tile (skinny-N shapes): BM=128 BN=64 BK=32 ----------
// Structural clone of k_gemm with the N-dimension halved: 4 waves as 2Mx2N,
// acc[4][2], 24KB LDS, 3 cp16/thread/stage (A:2, B:1) -> vmcnt(3) ledger.
// Audited r10: wave-uniform LDS bases (A: w*512; B: w*512 + lane*16B), vm3
// ledger (6 outstanding steady, oldest 3 = current tile), bounds exact.
// EPI: 0 = f32 store; 1 = bf16 store
template<int EPI>
__global__ __launch_bounds__(256) void k_gemm_n64(
    const u16* __restrict__ A, int lda,
    const u16* __restrict__ Bt, int ldb,
    int M, int N, int K,
    float* __restrict__ outF, u16* __restrict__ outB)
{
    __shared__ __align__(16) u16 As[2][4096];   // 128 rows x 32
    __shared__ __align__(16) u16 Bs[2][2048];   // 64 rows x 32
    int tid = threadIdx.x;
    int w = tid >> 6, lane = tid & 63;
    int bx, by; xcd_tile(bx, by);
    int m0 = by * 128, n0 = bx * 64;
    int wm = w & 1, wn = w >> 1;
    int lr = lane & 15, lq = lane >> 4;

    f32x4 acc[4][2];
    #pragma unroll
    for (int i = 0; i < 4; i++)
        #pragma unroll
        for (int j = 0; j < 2; j++) acc[i][j] = (f32x4)(0.f);

    int ar = tid >> 2;              // 0..63
    int ac = (tid & 3) * 8;
    const u16* Ag = A  + (size_t)(m0 + ar) * lda + ac;
    const u16* Bg = Bt + (size_t)(n0 + ar) * ldb + ac;
    int lo = w * 512;

    auto stage = [&](int kt, int s) {
        const u16* a  = Ag + kt * 32;
        const u16* bp = Bg + kt * 32;
        async_cp16(a,                     &As[s][lo]);
        async_cp16(a + (size_t)64 * lda,  &As[s][lo + 2048]);
        async_cp16(bp,                    &Bs[s][tid * 8]);
    };

    int nk = K >> 5;
    stage(0, 0);
    stage(1, 1);
    for (int k = 0; k < nk; k++) {
        if (k + 1 < nk) wait_vm3(); else wait_vm0();
        raw_barrier();
        int s = k & 1;
        s16x8 af[4], bfr[2];
        #pragma unroll
        for (int ms = 0; ms < 4; ms++)
            af[ms] = *reinterpret_cast<const s16x8*>(&As[s][(wm * 64 + ms * 16 + lr) * 32 + lq * 8]);
        #pragma unroll
        for (int ns = 0; ns < 2; ns++)
            bfr[ns] = *reinterpret_cast<const s16x8*>(&Bs[s][(wn * 32 + ns * 16 + lr) * 32 + lq * 8]);
        #pragma unroll
        for (int ms = 0; ms < 4; ms++)
            #pragma unroll
            for (int ns = 0; ns < 2; ns++)
                acc[ms][ns] = __builtin_amdgcn_mfma_f32_16x16x32_bf16(af[ms], bfr[ns], acc[ms][ns], 0, 0, 0);
        wait_lgkm0();
        raw_barrier();
        if (k + 2 < nk) stage(k + 2, s);
    }

    #pragma unroll
    for (int ms = 0; ms < 4; ms++) {
        #pragma unroll
        for (int ns = 0; ns < 2; ns++) {
            int col = n0 + wn * 32 + ns * 16 + lr;
            #pragma unroll
            for (int r = 0; r < 4; r++) {
                int row = m0 + wm * 64 + ms * 16 + lq * 4 + r;
                float v = acc[ms][ns][r];
                size_t idx = (size_t)row * N + col;
                if (EPI == 0) outF[idx] = v;
                else          outB[idx] = f2bf(v);
            }
        }
    }
}

// ---------- GEMM 64x64 tile (kept for the small weight-fuse GEMM) ----------
template<int EPI>
__global__ __launch_bounds__(256) void k_gemm64(
    const u16* __restrict__ A, int lda,
    const u16* __restrict__ Bt, int ldb,
    int M, int N, int K,
    float* __restrict__ outF, u16* __restrict__ outB)
{
    __shared__ __align__(16) u16 As[2][4096];   // [kc2][64 rows][32 u16]
    __shared__ __align__(16) u16 Bs[2][4096];
    int tid = threadIdx.x;
    int w = tid >> 6, lane = tid & 63;
    int bx, by; xcd_tile(bx, by);
    int m0 = by * 64, n0 = bx * 64;
    int wm = w & 1, wn = w >> 1;
    int lr = lane & 15, lq = lane >> 4;

    f32x4 acc[2][2];
    #pragma unroll
    for (int i = 0; i < 2; i++)
        #pragma unroll
        for (int j = 0; j < 2; j++) acc[i][j] = (f32x4)(0.f);

    int srow = tid >> 2;            // 0..63
    int sq   = tid & 3;             // 16B quarter within 32-u16 chunk
    const u16* Ag = A  + (size_t)(m0 + srow) * lda + sq * 8;
    const u16* Bg = Bt + (size_t)(n0 + srow) * ldb + sq * 8;
    int lo = srow * 32 + sq * 8;

    auto stage = [&](int kt, int s) {
        const u16* a  = Ag + kt * 64;
        const u16* bp = Bg + kt * 64;
        async_cp16(a,       &As[s][lo]);
        async_cp16(a + 32,  &As[s][2048 + lo]);
        async_cp16(bp,      &Bs[s][lo]);
        async_cp16(bp + 32, &Bs[s][2048 + lo]);
    };

    int nk = K >> 6;
    stage(0, 0);
    stage(1, 1);
    for (int k = 0; k < nk; k++) {
        if (k + 1 < nk) wait_vm4(); else wait_vm0();
        raw_barrier();
        int s = k & 1;
        s16x8 af[2][2], bfr[2][2];
        #pragma unroll
        for (int kc = 0; kc < 2; kc++) {
            #pragma unroll
            for (int ms = 0; ms < 2; ms++)
                af[ms][kc] = *reinterpret_cast<const s16x8*>(
                    &As[s][kc * 2048 + (wm * 32 + ms * 16 + lr) * 32 + lq * 8]);
            #pragma unroll
            for (int ns = 0; ns < 2; ns++)
                bfr[ns][kc] = *reinterpret_cast<const s16x8*>(
                    &Bs[s][kc * 2048 + (wn * 32 + ns * 16 + lr) * 32 + lq * 8]);
        }
        #pragma unroll
        for (int kc = 0; kc < 2; kc++)
            #pragma unroll
            for (int ms = 0; ms < 2; ms++)
                #pragma unroll
                for (int ns = 0; ns < 2; ns++)
                    acc[ms][ns] = __builtin_amdgcn_mfma_f32_16x16x32_bf16(
                        af[ms][kc], bfr[ns][kc], acc[ms][ns], 0, 0, 0);
        wait_lgkm0();
        raw_barrier();
        if (k + 2 < nk) stage(k + 2, s);
    }

    #pragma unroll
    for (int ms = 0; ms < 2; ms++) {
        #pragma unroll
        for (int ns = 0; ns < 2; ns++) {
            int col = n0 + wn * 32 + ns * 16 + lr;
            #pragma unroll
            for (int r = 0; r < 4; r++) {
                int row = m0 + wm * 32 + ms * 16 + lq * 4 + r;
                float v = acc[ms][ns][r];
                size_t idx = (size_t)row * N + col;
                if (EPI == 0) outF[idx] = v;
                else          outB[idx] = f2bf(v);
            }
        }
    }
}

// ---------- RoPE (x8 vectorized) ----------
__global__ __launch_bounds__(256) void k_rope(
    const u16* __restrict__ q, const u16* __restrict__ kv,
    const float* __restrict__ cosb, const float* __restrict__ sinb,
    u16* __restrict__ q_r, u16* __restrict__ k_r)
{
    const float QS = 0.125f * 1.4426950408889634f;
    int idx = blockIdx.x * 256 + threadIdx.x;    // B*T*H*8 threads
    int g = idx & 7;
    int h = (idx >> 3) & 15;
    int t = (idx >> 7) & 2047;
    int b = idx >> 18;
    size_t qsrc = ((size_t)((b * 2048 + t) * 16 + h)) * 64 + g * 8;
    size_t ksrc = ((size_t)((b * 2048 + t) * 16 + h)) * 128 + g * 8;
    u16x8 qa = *(const u16x8*)&q[qsrc];
    u16x8 ka = *(const u16x8*)&kv[ksrc];
    u16x8 qo, ko;
    if (g < 4) {
        int pd = ((g ^ 2) - g) * 8;
        u16x8 qp = *(const u16x8*)&q[qsrc + pd];
        u16x8 kp = *(const u16x8*)&kv[ksrc + pd];
        float sgn = (g < 2) ? -1.f : 1.f;
        const float* cp = &cosb[t * 32 + g * 8];
        const float* sp = &sinb[t * 32 + g * 8];
        #pragma unroll
        for (int j = 0; j < 8; j++) {
            float c = cp[j], s = sp[j];
            qo[j] = f2bf((bf2f(qa[j]) * c + sgn * bf2f(qp[j]) * s) * QS);
            ko[j] = f2bf(bf2f(ka[j]) * c + sgn * bf2f(kp[j]) * s);
        }
    } else {
        #pragma unroll
        for (int j = 0; j < 8; j++) {
            qo[j] = f2bf(bf2f(qa[j]) * QS);
            ko[j] = ka[j];
        }
    }
    size_t dst = ((size_t)(b * 16 + h) * 2048 + t) * 64 + g * 8;
    *(u16x8*)&q_r[dst] = qo;
    *(u16x8*)&k_r[dst] = ko;
}

// ---------- V transpose: kv [B,T,H,128] (v half) -> v_t [B,H,64,T] ----------
__global__ __launch_bounds__(256) void k_vtrans(
    const u16* __restrict__ kv, u16* __restrict__ v_t)
{
    __shared__ u16 tile[64][72];
    int bh = blockIdx.y;
    int b = bh >> 4, h = bh & 15;
    int t0 = blockIdx.x * 64;
    int tid = threadIdx.x;
    int r = tid >> 2;
    int c4 = (tid & 3) * 16;
    const u16* src = kv + ((size_t)((b * 2048 + t0 + r) * 16 + h)) * 128 + 64;
    #pragma unroll
    for (int j = 0; j < 16; j += 8)
        *(u16x8*)&tile[r][c4 + j] = *(const u16x8*)&src[c4 + j];
    __syncthreads();
    int dd = tid >> 2;
    u16* dst = v_t + ((size_t)bh * 64 + dd) * 2048 + t0;
    #pragma unroll
    for (int j0 = 0; j0 < 16; j0 += 8) {
        u16x8 vv;
        #pragma unroll
        for (int j = 0; j < 8; j++) vv[j] = tile[c4 + j0 + j][dd];
        *(u16x8*)&dst[c4 + j0] = vv;
    }
}

// ---------- flash attention v9 (verified 97us) ----------
// Keeps: XCD-partition remap (FETCH 139->41MB), pinned-zero C-operand, ones-MFMA
// row-sum, cvt_pk packing, 2-bit swizzle + dual ds_read_b64 V path,
// advancing-pointer staging, literal-offset 2x unroll, setprio, v_rcp epilogue.
// LDS analysis (r7): conflict-free; SQ_LDS_BANK_CONFLICT=2^23 is inherent
// multi-phase cycles of wide reads. Parked.
__global__ __launch_bounds__(256) void k_attn(
    const u16* __restrict__ q_r, const u16* __restrict__ k_r,
    const u16* __restrict__ v_t, u16* __restrict__ ctx)
{
    __shared__ __align__(16) u16 Ks[2][4096];
    __shared__ __align__(16) u16 Vs[2][4096];
    int tid = threadIdx.x, w = tid >> 6, lane = tid & 63;
    // XCD-partition remap (8 XCDs, grid 1024 = 8 xcd * 8 bh * 16 xb)
    int flat = blockIdx.x;
    int xcd = flat & 7;
    int idx = flat >> 3;
    int bh  = xcd * 8 + (idx & 7);
    int xb  = idx >> 3;                         // 0..15
    int b = bh >> 4, h = bh & 15;
    int q0 = xb * 128 + w * 32;
    const u16* Qp = q_r + (size_t)bh * 2048 * 64;
    const u16* Kp = k_r + (size_t)bh * 2048 * 64;
    const u16* Vp = v_t + (size_t)bh * 64 * 2048;
    int lr = lane & 15, lq = lane >> 4;
    int swz = (lr >> 1) & 3;                    // 2-bit read-side chunk16 XOR

    s16x8 qf[2][2];
    #pragma unroll
    for (int qc = 0; qc < 2; qc++)
        #pragma unroll
        for (int kf = 0; kf < 2; kf++)
            qf[qc][kf] = *(const s16x8*)&Qp[(size_t)(q0 + qc * 16 + lr) * 64 + kf * 32 + lq * 8];

    // bf16 1.0 fragment for the ones-MFMA row-sum
    s16x8 ones;
    #pragma unroll
    for (int j = 0; j < 8; j++) ones[j] = (short)0x3F80;

    // pinned zero quad for QK accumulator C-operand
    f32x4 fz = (f32x4)(0.f);
    asm("" : "+v"(fz));

    // staging: pre-swizzled global source, linear LDS dest (2-bit swizzle).
    int schunk = ((lane & 3) ^ ((lane >> 3) & 3)) * 8;
    const u16* gp;
    u16 *lp0, *lp1;
    size_t grow;
    int gAdv;
    if (w < 2) {
        gp = Kp + (size_t)(lane >> 2) * 64 + w * 32 + schunk;
        lp0 = &Ks[0][w * 2048]; lp1 = &Ks[1][w * 2048];
        grow = 16 * 64;  gAdv = 64 * 64;
    } else {
        gp = Vp + (size_t)(lane >> 2) * 2048 + (w - 2) * 32 + schunk;
        lp0 = &Vs[0][(w - 2) * 2048]; lp1 = &Vs[1][(w - 2) * 2048];
        grow = 16 * 2048; gAdv = 64;
    }
    auto stageP = [&](u16* lp) {
        #pragma unroll
        for (int g = 0; g < 4; g++)
            async_cp16(gp + g * grow, lp + g * 512);
        gp += gAdv;
    };

    f32x4 o[2][4];
    #pragma unroll
    for (int qt = 0; qt < 2; qt++)
        #pragma unroll
        for (int ds = 0; ds < 4; ds++) o[qt][ds] = (f32x4)(0.f);
    f32x4 lacc0 = (f32x4)(0.f), lacc1 = (f32x4)(0.f);

#define ATTN_BODY(S)                                                           \
  {                                                                            \
    f32x4 sc[2][4];                                                            \
    __builtin_amdgcn_s_setprio(1);                                             \
    _Pragma("unroll")                                                          \
    for (int ns = 0; ns < 4; ns++) {                                           \
      int ko = (ns * 16 + lr) * 32 + ((lq ^ swz) * 8);                         \
      s16x8 a0 = *(const s16x8*)&Ks[S][ko];                                    \
      s16x8 a1 = *(const s16x8*)&Ks[S][2048 + ko];                             \
      _Pragma("unroll")                                                        \
      for (int qc = 0; qc < 2; qc++) {                                         \
        f32x4 t;                                                               \
        t = __builtin_amdgcn_mfma_f32_16x16x32_bf16(a0, qf[qc][0], fz, 0, 0, 0);\
        t = __builtin_amdgcn_mfma_f32_16x16x32_bf16(a1, qf[qc][1], t, 0, 0, 0);\
        sc[qc][ns] = t;                                                        \
      }                                                                        \
    }                                                                          \
    __builtin_amdgcn_s_setprio(0);                                             \
    _Pragma("unroll")                                                          \
    for (int kf = 0; kf < 2; kf++) {                                           \
      u32x4 w0, w1;                                                            \
      _Pragma("unroll")                                                        \
      for (int j = 0; j < 4; j++) {                                            \
        int ns = kf * 2 + (j >> 1);                                            \
        int r0 = (j & 1) * 2;                                                  \
        float ea = fast_exp2(sc[0][ns][r0]);                                   \
        float eb = fast_exp2(sc[0][ns][r0 + 1]);                               \
        float ec = fast_exp2(sc[1][ns][r0]);                                   \
        float ed = fast_exp2(sc[1][ns][r0 + 1]);                               \
        uint32_t t0, t1;                                                       \
        asm("v_cvt_pk_bf16_f32 %0, %1, %2" : "=v"(t0) : "v"(ea), "v"(eb));     \
        asm("v_cvt_pk_bf16_f32 %0, %1, %2" : "=v"(t1) : "v"(ec), "v"(ed));     \
        w0[j] = t0; w1[j] = t1;                                                \
      }                                                                        \
      s16x8 pk0 = __builtin_bit_cast(s16x8, w0);                               \
      s16x8 pk1 = __builtin_bit_cast(s16x8, w1);                               \
      __builtin_amdgcn_s_setprio(1);                                           \
      lacc0 = __builtin_amdgcn_mfma_f32_16x16x32_bf16(pk0, ones, lacc0, 0,0,0);\
      lacc1 = __builtin_amdgcn_mfma_f32_16x16x32_bf16(pk1, ones, lacc1, 0,0,0);\
      _Pragma("unroll")                                                        \
      for (int ds = 0; ds < 4; ds++) {                                         \
        int vbase = kf * 2048 + (ds * 16 + lr) * 32 + (lq & 1) * 4;            \
        s16x4 vlo = *(const s16x4*)&Vs[S][vbase + (((lq >> 1)    ) ^ swz) * 8];\
        s16x4 vhi = *(const s16x4*)&Vs[S][vbase + (((lq >> 1) | 2) ^ swz) * 8];\
        s16x8 vf = __builtin_shufflevector(vlo, vhi, 0, 1, 2, 3, 4, 5, 6, 7);  \
        o[0][ds] = __builtin_amdgcn_mfma_f32_16x16x32_bf16(pk0, vf, o[0][ds], 0, 0, 0);\
        o[1][ds] = __builtin_amdgcn_mfma_f32_16x16x32_bf16(pk1, vf, o[1][ds], 0, 0, 0);\
      }                                                                        \
      __builtin_amdgcn_s_setprio(0);                                           \
    }                                                                          \
  }

    stageP(lp0);   // tile 0 -> buf0
    stageP(lp1);   // tile 1 -> buf1
    for (int k2 = 0; k2 < 15; k2++) {
        wait_vm4(); raw_barrier();
        ATTN_BODY(0)
        wait_lgkm0(); raw_barrier();
        stageP(lp0);
        wait_vm4(); raw_barrier();
        ATTN_BODY(1)
        wait_lgkm0(); raw_barrier();
        stageP(lp1);
    }
    wait_vm4(); raw_barrier();
    ATTN_BODY(0)
    wait_vm0(); raw_barrier();
    ATTN_BODY(1)
#undef ATTN_BODY

    #pragma unroll
    for (int qt = 0; qt < 2; qt++) {
        f32x4 lv = qt ? lacc1 : lacc0;
        float li[4];
        #pragma unroll
        for (int r = 0; r < 4; r++) li[r] = __builtin_amdgcn_rcpf(lv[r]);
        #pragma unroll
        for (int ds = 0; ds < 4; ds++)
            #pragma unroll
            for (int r = 0; r < 4; r++) {
                int tq = q0 + qt * 16 + lq * 4 + r;
                float v = o[qt][ds][r] * li[r];
                ctx[((size_t)(b * 2048) + tq) * 1024 + h * 64 + ds * 16 + lr] = f2bf(v);
            }
    }
}

// ---------- host ----------
extern "C" void kernel_launch(void* const* d_in, const int* in_sizes, int n_in,
                              void* d_out, int out_size, void* d_ws, size_t ws_size,
                              hipStream_t stream) {
    (void)in_sizes; (void)n_in; (void)out_size; (void)ws_size;
    const float* x     = (const float*)d_in[0];
    const float* ln1   = (const float*)d_in[1];
    const float* alnw  = (const float*)d_in[2];
    const float* qkv_a = (const float*)d_in[3];
    const float* q_b   = (const float*)d_in[4];
    const float* kv_b  = (const float*)d_in[5];
    const float* o_a   = (const float*)d_in[6];
    const float* o_b   = (const float*)d_in[7];
    const float* ln2   = (const float*)d_in[8];
    const float* in_a  = (const float*)d_in[9];
    const float* in_b  = (const float*)d_in[10];
    const float* out_a = (const float*)d_in[11];
    const float* out_b = (const float*)d_in[12];
    const float* cosb  = (const float*)d_in[13];
    const float* sinb  = (const float*)d_in[14];
    float* out = (float*)d_out;
    char* ws = (char*)d_ws;

    // ---- weights bf16 [0, 15728640) ----
    u16* wqkv = (u16*)ws;              // 768x1024
    u16* wq   = wqkv + 786432;         // 1024x512
    u16* wkv  = wq   + 524288;         // 2048x256
    u16* wob  = wkv  + 524288;         // 1024x512 (o_b^T)
    u16* wia  = wob  + 524288;         // 384x1024
    u16* wib  = wia  + 393216;         // 4096x384
    u16* woa2 = wib  + 1572864;        // 384x4096 (out_a^T)
    u16* wob2 = woa2 + 1572864;        // 1024x384
    u16* woan = wob2 + 393216;         // 1024x512 (o_a cast)
    u16* woab = woan + 524288;         // 1024x1024 fused (o_a@o_b)^T

    // ---- activations, base G = ws + 15728640 ----
    char* G = ws + 15728640;
    u16*  hbuf  = (u16*)(G + 0);              // 16.8 MB [rms1 -> qkv]
    float* lat_raw = (float*)(G + 16777216);  // 25.2 MB [qkv -> rms768]
    u16*  lat   = (u16*)(G + 41943040);       // 12.6 MB [rms768 -> q,kv]
    u16*  qbuf  = (u16*)(G + 54525952);       // 16.8 MB [q -> rope]
    u16*  kvbuf = (u16*)(G + 71303168);       // 33.6 MB [kv -> rope,vtrans]
    u16*  q_r   = (u16*)(G + 0);              // reuse hbuf      [rope -> attn]
    u16*  k_r   = (u16*)(G + 16777216);       // reuse lat_raw   [rope -> attn]
    u16*  v_t   = (u16*)(G + 33554432);       // lat_raw tail+lat [vtrans -> attn]
    u16*  ctx   = (u16*)(G + 54525952);       // reuse qbuf      [attn -> o-gemm]
    float* x2   = (float*)(G + 0);            // 33.6 MB, reuse q_r/k_r [o -> final]
    u16*  h2    = (u16*)(G + 33554432);       // reuse v_t       [rms2 -> in_a]
    u16*  t1    = (u16*)(G + 50331648);       // 6.3 MB          [in_a -> in_b]
    u16*  t2    = (u16*)(G + 56623104);       // 64 MB           [in_b -> out_a]
    u16*  t3    = (u16*)(G + 50331648);       // reuse t1        [out_a -> out_b]

    TPack tp;
    tp.t[0] = { qkv_a, wqkv, 1024, 768,  0 };
    tp.t[1] = { q_b,   wq,   512,  1024, 768 };
    tp.t[2] = { kv_b,  wkv,  256,  2048, 1280 };
    tp.t[3] = { o_b,   wob,  512,  1024, 1792 };
    tp.t[4] = { in_a,  wia,  1024, 384,  2304 };
    tp.t[5] = { in_b,  wib,  384,  4096, 2688 };
    tp.t[6] = { out_a, woa2, 4096, 384,  4224 };
    tp.t[7] = { out_b, wob2, 384,  1024, 5760 };
    k_transpose_all<<<6144, dim3(32, 8), 0, stream>>>(tp);
    k_cvt<<<512, 256, 0, stream>>>(o_a, woan);
    // fused o-weight: W^T = o_b^T @ o_a  (bf16), [1024][1024]
    k_gemm64<1><<<dim3(16, 16), 256, 0, stream>>>(wob, 512, woan, 512, 1024, 1024, 512, nullptr, woab);

    k_rmsnorm<1024><<<NTOK, 256, 0, stream>>>(x, ln1, hbuf);
    // qkv: 128x64 tile: grid 12x64 = 768 blocks (3/CU)
    k_gemm_n64<0><<<dim3(12, 64), 256, 0, stream>>>(hbuf, 1024, wqkv, 1024, NTOK, 768, 1024, lat_raw, nullptr);
    k_rmsnorm<768><<<NTOK, 256, 0, stream>>>(lat_raw, alnw, lat);
    k_gemm<1><<<dim3(8, 64),  256, 0, stream>>>(lat,       768, wq,  512, NTOK, 1024, 512, nullptr, qbuf,  nullptr);
    k_gemm<1><<<dim3(16, 64), 256, 0, stream>>>(lat + 512, 768, wkv, 256, NTOK, 2048, 256, nullptr, kvbuf, nullptr);
    k_rope<<<4096, 256, 0, stream>>>(qbuf, kvbuf, cosb, sinb, q_r, k_r);
    k_vtrans<<<dim3(32, 64), 256, 0, stream>>>(kvbuf, v_t);
    k_attn<<<1024, 256, 0, stream>>>(q_r, k_r, v_t, ctx);
    // attn_out + residual in one GEMM via fused weight
    k_gemm<3><<<dim3(8, 64), 256, 0, stream>>>(ctx, 1024, woab, 1024, NTOK, 1024, 1024, x2, nullptr, x);
    k_rmsnorm<1024><<<NTOK, 256, 0, stream>>>(x2, ln2, h2);
    // ffn in_a: 128x64 tile: grid 6x64 = 384 blocks
    k_gemm_n64<1><<<dim3(6, 64), 256, 0, stream>>>(h2, 1024, wia, 1024, NTOK, 384, 1024, nullptr, t1);
    k_gemm<2><<<dim3(32, 64), 256, 0, stream>>>(t1, 384, wib, 384, NTOK, 4096, 384, nullptr, t2, nullptr);
    // ffn out_a: 128x64 tile, K=4096 deep: grid 6x64 = 384 blocks
    k_gemm_n64<1><<<dim3(6, 64), 256, 0, stream>>>(t2, 4096, woa2, 4096, NTOK, 384, 4096, nullptr, t3);
    k_gemm<3><<<dim3(8, 64), 256, 0, stream>>>(t3, 384, wob2, 384, NTOK, 1024, 384, out, nullptr, x2);
}

// Round 12
// 467.289 us; speedup vs baseline: 1.0762x; 1.0468x over previous
//
#include <hip/hip_runtime.h>
#include <hip/hip_bf16.h>
#include <stdint.h>

// ---------- problem constants ----------
#define NTOK 8192   // B*T

typedef unsigned short u16;
typedef __attribute__((ext_vector_type(4))) float f32x4;
typedef __attribute__((ext_vector_type(8))) short s16x8;
typedef __attribute__((ext_vector_type(4))) short s16x4;
typedef __attribute__((ext_vector_type(8))) u16   u16x8;
typedef __attribute__((ext_vector_type(4))) u16   u16x4;
typedef __attribute__((ext_vector_type(4))) uint32_t u32x4;

__device__ __forceinline__ float fast_exp2(float x) {
    return __builtin_amdgcn_exp2f(x);
}
__device__ __forceinline__ u16 f2bf(float f) {
    uint32_t u = __float_as_uint(f);
    u = (u + 0x7FFFu + ((u >> 16) & 1u)) >> 16;   // RNE
    return (u16)u;
}
__device__ __forceinline__ float bf2f(u16 h) {
    return __uint_as_float(((uint32_t)h) << 16);
}
__device__ __forceinline__ void async_cp16(const void* g, void* l) {
    __builtin_amdgcn_global_load_lds(
        (const __attribute__((address_space(1))) void*)g,
        (__attribute__((address_space(3))) void*)l, 16, 0, 0);
}
__device__ __forceinline__ void wait_vm4()   { asm volatile("s_waitcnt vmcnt(4)" ::: "memory"); }
__device__ __forceinline__ void wait_vm0()   { asm volatile("s_waitcnt vmcnt(0)" ::: "memory"); }
__device__ __forceinline__ void wait_lgkm0() { asm volatile("s_waitcnt lgkmcnt(0)" ::: "memory"); }
__device__ __forceinline__ void raw_barrier(){ asm volatile("s_barrier" ::: "memory"); }

// XCD-aware tile remap (T1): dispatch order round-robins XCDs; give XCD k a
// CONTIGUOUS chunk of work tiles so same-XCD blocks share A-panels in its L2.
// Requires nwg % 8 == 0 (true for every grid below).
// r8 A/B: +45us total. r9/r11 tile sweep: skinny GEMMs are occupancy-bound
// (64^2 @6 blk/CU = 465 < 128x64 @3 = 489 < 128^2 @1.5 = 503) -> keep 64^2.
__device__ __forceinline__ void xcd_tile(int& bx, int& by) {
    int gx = gridDim.x;
    int nwg = gx * gridDim.y;
    int flat = blockIdx.y * gx + blockIdx.x;
    int swz = (flat & 7) * (nwg >> 3) + (flat >> 3);
    bx = swz % gx;
    by = swz / gx;
}

// ---------- all weight transposes in one launch: f32 [K][N] -> bf16 [N][K] ----------
struct TDesc { const float* s; u16* d; int K; int N; int tile0; };
struct TPack { TDesc t[8]; };

__global__ __launch_bounds__(256) void k_transpose_all(TPack p)
{
    __shared__ float tile[32][33];
    int bid = blockIdx.x;
    int i = 0;
    #pragma unroll
    for (int j = 1; j < 8; j++) if (bid >= p.t[j].tile0) i = j;
    const float* src = p.t[i].s;
    u16* dst = p.t[i].d;
    int K = p.t[i].K, N = p.t[i].N;
    int local = bid - p.t[i].tile0;
    int nx = N >> 5;
    int n0 = (local % nx) * 32, k0 = (local / nx) * 32;
    int tx = threadIdx.x, ty = threadIdx.y;      // block (32,8)
    #pragma unroll
    for (int r = 0; r < 32; r += 8)
        tile[ty + r][tx] = src[(size_t)(k0 + ty + r) * N + n0 + tx];
    __syncthreads();
    #pragma unroll
    for (int r = 0; r < 32; r += 8)
        dst[(size_t)(n0 + ty + r) * K + k0 + tx] = f2bf(tile[tx][ty + r]);
}

// ---------- f32 -> bf16 flat convert ----------
__global__ __launch_bounds__(256) void k_cvt(
    const float* __restrict__ in, u16* __restrict__ out)
{
    int i = (blockIdx.x * 256 + threadIdx.x) * 4;
    f32x4 v = *(const f32x4*)&in[i];
    u16x4 o;
    #pragma unroll
    for (int j = 0; j < 4; j++) o[j] = f2bf(v[j]);
    *(u16x4*)&out[i] = o;
}

// ---------- RMSNorm: f32 in, bf16 out ----------
template<int W>
__global__ __launch_bounds__(256) void k_rmsnorm(
    const float* __restrict__ x, const float* __restrict__ w, u16* __restrict__ out)
{
    constexpr int E = W / 256;
    int row = blockIdx.x, tid = threadIdx.x;
    const float* xr = x + (size_t)row * W;
    float v[E]; float ss = 0.f;
    #pragma unroll
    for (int i = 0; i < E; i++) { v[i] = xr[tid + i * 256]; ss += v[i] * v[i]; }
    #pragma unroll
    for (int m = 1; m < 64; m <<= 1) ss += __shfl_xor(ss, m, 64);
    __shared__ float red[4];
    if ((tid & 63) == 0) red[tid >> 6] = ss;
    __syncthreads();
    ss = red[0] + red[1] + red[2] + red[3];
    float scale = rsqrtf(ss / (float)W + 1e-6f);
    u16* orow = out + (size_t)row * W;
    #pragma unroll
    for (int i = 0; i < E; i++)
        orow[tid + i * 256] = f2bf(w[tid + i * 256] * (v[i] * scale));
}

// ---------- GEMM 128x128 tile, double-buffered pipelined K-loop ----------
// EPI: 0 = f32 store; 1 = bf16 store; 2 = gelu(tanh)+bf16; 3 = f32 + resid
template<int EPI>
__global__ __launch_bounds__(256) void k_gemm(
    const u16* __restrict__ A, int lda,
    const u16* __restrict__ Bt, int ldb,
    int M, int N, int K,
    float* __restrict__ outF, u16* __restrict__ outB,
    const float* __restrict__ resid)
{
    __shared__ __align__(16) u16 As[2][4096];
    __shared__ __align__(16) u16 Bs[2][4096];
    int tid = threadIdx.x;
    int w = tid >> 6, lane = tid & 63;
    int bx, by; xcd_tile(bx, by);
    int m0 = by * 128, n0 = bx * 128;
    int wm = w & 1, wn = w >> 1;
    int lr = lane & 15, lq = lane >> 4;

    f32x4 acc[4][4];
    #pragma unroll
    for (int i = 0; i < 4; i++)
        #pragma unroll
        for (int j = 0; j < 4; j++) acc[i][j] = (f32x4)(0.f);

    int ar = tid >> 2;
    int ac = (tid & 3) * 8;
    const u16* Ag = A  + (size_t)(m0 + ar) * lda + ac;
    const u16* Bg = Bt + (size_t)(n0 + ar) * ldb + ac;
    int lo = w * 512;

    auto stage = [&](int kt, int s) {
        const u16* a  = Ag + kt * 32;
        const u16* bp = Bg + kt * 32;
        async_cp16(a,                     &As[s][lo]);
        async_cp16(a + (size_t)64 * lda,  &As[s][lo + 2048]);
        async_cp16(bp,                    &Bs[s][lo]);
        async_cp16(bp + (size_t)64 * ldb, &Bs[s][lo + 2048]);
    };

    int nk = K >> 5;
    stage(0, 0);
    stage(1, 1);
    for (int k = 0; k < nk; k++) {
        if (k + 1 < nk) wait_vm4(); else wait_vm0();
        raw_barrier();
        int s = k & 1;
        s16x8 af[4], bfr[4];
        #pragma unroll
        for (int ms = 0; ms < 4; ms++)
            af[ms] = *reinterpret_cast<const s16x8*>(&As[s][(wm * 64 + ms * 16 + lr) * 32 + lq * 8]);
        #pragma unroll
        for (int ns = 0; ns < 4; ns++)
            bfr[ns] = *reinterpret_cast<const s16x8*>(&Bs[s][(wn * 64 + ns * 16 + lr) * 32 + lq * 8]);
        #pragma unroll
        for (int ms = 0; ms < 4; ms++)
            #pragma unroll
            for (int ns = 0; ns < 4; ns++)
                acc[ms][ns] = __builtin_amdgcn_mfma_f32_16x16x32_bf16(af[ms], bfr[ns], acc[ms][ns], 0, 0, 0);
        wait_lgkm0();
        raw_barrier();
        if (k + 2 < nk) stage(k + 2, s);
    }

    #pragma unroll
    for (int ms = 0; ms < 4; ms++) {
        #pragma unroll
        for (int ns = 0; ns < 4; ns++) {
            int col = n0 + wn * 64 + ns * 16 + lr;
            #pragma unroll
            for (int r = 0; r < 4; r++) {
                int row = m0 + wm * 64 + ms * 16 + lq * 4 + r;
                float v = acc[ms][ns][r];
                size_t idx = (size_t)row * N + col;
                if (EPI == 0) {
                    outF[idx] = v;
                } else if (EPI == 1) {
                    outB[idx] = f2bf(v);
                } else if (EPI == 2) {
                    // gelu(tanh) via exp2+rcp: 0.5v(1+tanh t) = v - v/(1+e^{2t})
                    float t = 0.7978845608028654f * (v + 0.044715f * v * v * v);
                    float e = fast_exp2(t * 2.8853900817779268f);
                    outB[idx] = f2bf(v - v * __builtin_amdgcn_rcpf(1.f + e));
                } else {
                    outF[idx] = v + resid[idx];
                }
            }
        }
    }
}

// ---------- GEMM 64x64 tile (skinny-N, occupancy-bound shapes) ----------
template<int EPI>
__global__ __launch_bounds__(256) void k_gemm64(
    const u16* __restrict__ A, int lda,
    const u16* __restrict__ Bt, int ldb,
    int M, int N, int K,
    float* __restrict__ outF, u16* __restrict__ outB)
{
    __shared__ __align__(16) u16 As[2][4096];   // [kc2][64 rows][32 u16]
    __shared__ __align__(16) u16 Bs[2][4096];
    int tid = threadIdx.x;
    int w = tid >> 6, lane = tid & 63;
    int bx, by; xcd_tile(bx, by);
    int m0 = by * 64, n0 = bx * 64;
    int wm = w & 1, wn = w >> 1;
    int lr = lane & 15, lq = lane >> 4;

    f32x4 acc[2][2];
    #pragma unroll
    for (int i = 0; i < 2; i++)
        #pragma unroll
        for (int j = 0; j < 2; j++) acc[i][j] = (f32x4)(0.f);

    int srow = tid >> 2;            // 0..63
    int sq   = tid & 3;             // 16B quarter within 32-u16 chunk
    const u16* Ag = A  + (size_t)(m0 + srow) * lda + sq * 8;
    const u16* Bg = Bt + (size_t)(n0 + srow) * ldb + sq * 8;
    int lo = srow * 32 + sq * 8;

    auto stage = [&](int kt, int s) {
        const u16* a  = Ag + kt * 64;
        const u16* bp = Bg + kt * 64;
        async_cp16(a,       &As[s][lo]);
        async_cp16(a + 32,  &As[s][2048 + lo]);
        async_cp16(bp,      &Bs[s][lo]);
        async_cp16(bp + 32, &Bs[s][2048 + lo]);
    };

    int nk = K >> 6;
    stage(0, 0);
    stage(1, 1);
    for (int k = 0; k < nk; k++) {
        if (k + 1 < nk) wait_vm4(); else wait_vm0();
        raw_barrier();
        int s = k & 1;
        s16x8 af[2][2], bfr[2][2];
        #pragma unroll
        for (int kc = 0; kc < 2; kc++) {
            #pragma unroll
            for (int ms = 0; ms < 2; ms++)
                af[ms][kc] = *reinterpret_cast<const s16x8*>(
                    &As[s][kc * 2048 + (wm * 32 + ms * 16 + lr) * 32 + lq * 8]);
            #pragma unroll
            for (int ns = 0; ns < 2; ns++)
                bfr[ns][kc] = *reinterpret_cast<const s16x8*>(
                    &Bs[s][kc * 2048 + (wn * 32 + ns * 16 + lr) * 32 + lq * 8]);
        }
        #pragma unroll
        for (int kc = 0; kc < 2; kc++)
            #pragma unroll
            for (int ms = 0; ms < 2; ms++)
                #pragma unroll
                for (int ns = 0; ns < 2; ns++)
                    acc[ms][ns] = __builtin_amdgcn_mfma_f32_16x16x32_bf16(
                        af[ms][kc], bfr[ns][kc], acc[ms][ns], 0, 0, 0);
        wait_lgkm0();
        raw_barrier();
        if (k + 2 < nk) stage(k + 2, s);
    }

    #pragma unroll
    for (int ms = 0; ms < 2; ms++) {
        #pragma unroll
        for (int ns = 0; ns < 2; ns++) {
            int col = n0 + wn * 32 + ns * 16 + lr;
            #pragma unroll
            for (int r = 0; r < 4; r++) {
                int row = m0 + wm * 32 + ms * 16 + lq * 4 + r;
                float v = acc[ms][ns][r];
                size_t idx = (size_t)row * N + col;
                if (EPI == 0) outF[idx] = v;
                else          outB[idx] = f2bf(v);
            }
        }
    }
}

// ---------- RoPE (x8 vectorized) ----------
__global__ __launch_bounds__(256) void k_rope(
    const u16* __restrict__ q, const u16* __restrict__ kv,
    const float* __restrict__ cosb, const float* __restrict__ sinb,
    u16* __restrict__ q_r, u16* __restrict__ k_r)
{
    const float QS = 0.125f * 1.4426950408889634f;
    int idx = blockIdx.x * 256 + threadIdx.x;    // B*T*H*8 threads
    int g = idx & 7;
    int h = (idx >> 3) & 15;
    int t = (idx >> 7) & 2047;
    int b = idx >> 18;
    size_t qsrc = ((size_t)((b * 2048 + t) * 16 + h)) * 64 + g * 8;
    size_t ksrc = ((size_t)((b * 2048 + t) * 16 + h)) * 128 + g * 8;
    u16x8 qa = *(const u16x8*)&q[qsrc];
    u16x8 ka = *(const u16x8*)&kv[ksrc];
    u16x8 qo, ko;
    if (g < 4) {
        int pd = ((g ^ 2) - g) * 8;
        u16x8 qp = *(const u16x8*)&q[qsrc + pd];
        u16x8 kp = *(const u16x8*)&kv[ksrc + pd];
        float sgn = (g < 2) ? -1.f : 1.f;
        const float* cp = &cosb[t * 32 + g * 8];
        const float* sp = &sinb[t * 32 + g * 8];
        #pragma unroll
        for (int j = 0; j < 8; j++) {
            float c = cp[j], s = sp[j];
            qo[j] = f2bf((bf2f(qa[j]) * c + sgn * bf2f(qp[j]) * s) * QS);
            ko[j] = f2bf(bf2f(ka[j]) * c + sgn * bf2f(kp[j]) * s);
        }
    } else {
        #pragma unroll
        for (int j = 0; j < 8; j++) {
            qo[j] = f2bf(bf2f(qa[j]) * QS);
            ko[j] = ka[j];
        }
    }
    size_t dst = ((size_t)(b * 16 + h) * 2048 + t) * 64 + g * 8;
    *(u16x8*)&q_r[dst] = qo;
    *(u16x8*)&k_r[dst] = ko;
}

// ---------- V transpose: kv [B,T,H,128] (v half) -> v_t [B,H,64,T] ----------
__global__ __launch_bounds__(256) void k_vtrans(
    const u16* __restrict__ kv, u16* __restrict__ v_t)
{
    __shared__ u16 tile[64][72];
    int bh = blockIdx.y;
    int b = bh >> 4, h = bh & 15;
    int t0 = blockIdx.x * 64;
    int tid = threadIdx.x;
    int r = tid >> 2;
    int c4 = (tid & 3) * 16;
    const u16* src = kv + ((size_t)((b * 2048 + t0 + r) * 16 + h)) * 128 + 64;
    #pragma unroll
    for (int j = 0; j < 16; j += 8)
        *(u16x8*)&tile[r][c4 + j] = *(const u16x8*)&src[c4 + j];
    __syncthreads();
    int dd = tid >> 2;
    u16* dst = v_t + ((size_t)bh * 64 + dd) * 2048 + t0;
    #pragma unroll
    for (int j0 = 0; j0 < 16; j0 += 8) {
        u16x8 vv;
        #pragma unroll
        for (int j = 0; j < 8; j++) vv[j] = tile[c4 + j0 + j][dd];
        *(u16x8*)&dst[c4 + j0] = vv;
    }
}

// ---------- flash attention v9 (verified 97us) ----------
// Keeps: XCD-partition remap (FETCH 139->41MB), pinned-zero C-operand, ones-MFMA
// row-sum, cvt_pk packing, 2-bit swizzle + dual ds_read_b64 V path,
// advancing-pointer staging, literal-offset 2x unroll, setprio, v_rcp epilogue.
// LDS analysis (r7): conflict-free; SQ_LDS_BANK_CONFLICT=2^23 is inherent
// multi-phase cycles of wide reads. Parked.
__global__ __launch_bounds__(256) void k_attn(
    const u16* __restrict__ q_r, const u16* __restrict__ k_r,
    const u16* __restrict__ v_t, u16* __restrict__ ctx)
{
    __shared__ __align__(16) u16 Ks[2][4096];
    __shared__ __align__(16) u16 Vs[2][4096];
    int tid = threadIdx.x, w = tid >> 6, lane = tid & 63;
    // XCD-partition remap (8 XCDs, grid 1024 = 8 xcd * 8 bh * 16 xb)
    int flat = blockIdx.x;
    int xcd = flat & 7;
    int idx = flat >> 3;
    int bh  = xcd * 8 + (idx & 7);
    int xb  = idx >> 3;                         // 0..15
    int b = bh >> 4, h = bh & 15;
    int q0 = xb * 128 + w * 32;
    const u16* Qp = q_r + (size_t)bh * 2048 * 64;
    const u16* Kp = k_r + (size_t)bh * 2048 * 64;
    const u16* Vp = v_t + (size_t)bh * 64 * 2048;
    int lr = lane & 15, lq = lane >> 4;
    int swz = (lr >> 1) & 3;                    // 2-bit read-side chunk16 XOR

    s16x8 qf[2][2];
    #pragma unroll
    for (int qc = 0; qc < 2; qc++)
        #pragma unroll
        for (int kf = 0; kf < 2; kf++)
            qf[qc][kf] = *(const s16x8*)&Qp[(size_t)(q0 + qc * 16 + lr) * 64 + kf * 32 + lq * 8];

    // bf16 1.0 fragment for the ones-MFMA row-sum
    s16x8 ones;
    #pragma unroll
    for (int j = 0; j < 8; j++) ones[j] = (short)0x3F80;

    // pinned zero quad for QK accumulator C-operand
    f32x4 fz = (f32x4)(0.f);
    asm("" : "+v"(fz));

    // staging: pre-swizzled global source, linear LDS dest (2-bit swizzle).
    int schunk = ((lane & 3) ^ ((lane >> 3) & 3)) * 8;
    const u16* gp;
    u16 *lp0, *lp1;
    size_t grow;
    int gAdv;
    if (w < 2) {
        gp = Kp + (size_t)(lane >> 2) * 64 + w * 32 + schunk;
        lp0 = &Ks[0][w * 2048]; lp1 = &Ks[1][w * 2048];
        grow = 16 * 64;  gAdv = 64 * 64;
    } else {
        gp = Vp + (size_t)(lane >> 2) * 2048 + (w - 2) * 32 + schunk;
        lp0 = &Vs[0][(w - 2) * 2048]; lp1 = &Vs[1][(w - 2) * 2048];
        grow = 16 * 2048; gAdv = 64;
    }
    auto stageP = [&](u16* lp) {
        #pragma unroll
        for (int g = 0; g < 4; g++)
            async_cp16(gp + g * grow, lp + g * 512);
        gp += gAdv;
    };

    f32x4 o[2][4];
    #pragma unroll
    for (int qt = 0; qt < 2; qt++)
        #pragma unroll
        for (int ds = 0; ds < 4; ds++) o[qt][ds] = (f32x4)(0.f);
    f32x4 lacc0 = (f32x4)(0.f), lacc1 = (f32x4)(0.f);

#define ATTN_BODY(S)                                                           \
  {                                                                            \
    f32x4 sc[2][4];                                                            \
    __builtin_amdgcn_s_setprio(1);                                             \
    _Pragma("unroll")                                                          \
    for (int ns = 0; ns < 4; ns++) {                                           \
      int ko = (ns * 16 + lr) * 32 + ((lq ^ swz) * 8);                         \
      s16x8 a0 = *(const s16x8*)&Ks[S][ko];                                    \
      s16x8 a1 = *(const s16x8*)&Ks[S][2048 + ko];                             \
      _Pragma("unroll")                                                        \
      for (int qc = 0; qc < 2; qc++) {                                         \
        f32x4 t;                                                               \
        t = __builtin_amdgcn_mfma_f32_16x16x32_bf16(a0, qf[qc][0], fz, 0, 0, 0);\
        t = __builtin_amdgcn_mfma_f32_16x16x32_bf16(a1, qf[qc][1], t, 0, 0, 0);\
        sc[qc][ns] = t;                                                        \
      }                                                                        \
    }                                                                          \
    __builtin_amdgcn_s_setprio(0);                                             \
    _Pragma("unroll")                                                          \
    for (int kf = 0; kf < 2; kf++) {                                           \
      u32x4 w0, w1;                                                            \
      _Pragma("unroll")                                                        \
      for (int j = 0; j < 4; j++) {                                            \
        int ns = kf * 2 + (j >> 1);                                            \
        int r0 = (j & 1) * 2;                                                  \
        float ea = fast_exp2(sc[0][ns][r0]);                                   \
        float eb = fast_exp2(sc[0][ns][r0 + 1]);                               \
        float ec = fast_exp2(sc[1][ns][r0]);                                   \
        float ed = fast_exp2(sc[1][ns][r0 + 1]);                               \
        uint32_t t0, t1;                                                       \
        asm("v_cvt_pk_bf16_f32 %0, %1, %2" : "=v"(t0) : "v"(ea), "v"(eb));     \
        asm("v_cvt_pk_bf16_f32 %0, %1, %2" : "=v"(t1) : "v"(ec), "v"(ed));     \
        w0[j] = t0; w1[j] = t1;                                                \
      }                                                                        \
      s16x8 pk0 = __builtin_bit_cast(s16x8, w0);                               \
      s16x8 pk1 = __builtin_bit_cast(s16x8, w1);                               \
      __builtin_amdgcn_s_setprio(1);                                           \
      lacc0 = __builtin_amdgcn_mfma_f32_16x16x32_bf16(pk0, ones, lacc0, 0,0,0);\
      lacc1 = __builtin_amdgcn_mfma_f32_16x16x32_bf16(pk1, ones, lacc1, 0,0,0);\
      _Pragma("unroll")                                                        \
      for (int ds = 0; ds < 4; ds++) {                                         \
        int vbase = kf * 2048 + (ds * 16 + lr) * 32 + (lq & 1) * 4;            \
        s16x4 vlo = *(const s16x4*)&Vs[S][vbase + (((lq >> 1)    ) ^ swz) * 8];\
        s16x4 vhi = *(const s16x4*)&Vs[S][vbase + (((lq >> 1) | 2) ^ swz) * 8];\
        s16x8 vf = __builtin_shufflevector(vlo, vhi, 0, 1, 2, 3, 4, 5, 6, 7);  \
        o[0][ds] = __builtin_amdgcn_mfma_f32_16x16x32_bf16(pk0, vf, o[0][ds], 0, 0, 0);\
        o[1][ds] = __builtin_amdgcn_mfma_f32_16x16x32_bf16(pk1, vf, o[1][ds], 0, 0, 0);\
      }                                                                        \
      __builtin_amdgcn_s_setprio(0);                                           \
    }                                                                          \
  }

    stageP(lp0);   // tile 0 -> buf0
    stageP(lp1);   // tile 1 -> buf1
    for (int k2 = 0; k2 < 15; k2++) {
        wait_vm4(); raw_barrier();
        ATTN_BODY(0)
        wait_lgkm0(); raw_barrier();
        stageP(lp0);
        wait_vm4(); raw_barrier();
        ATTN_BODY(1)
        wait_lgkm0(); raw_barrier();
        stageP(lp1);
    }
    wait_vm4(); raw_barrier();
    ATTN_BODY(0)
    wait_vm0(); raw_barrier();
    ATTN_BODY(1)
#undef ATTN_BODY

    #pragma unroll
    for (int qt = 0; qt < 2; qt++) {
        f32x4 lv = qt ? lacc1 : lacc0;
        float li[4];
        #pragma unroll
        for (int r = 0; r < 4; r++) li[r] = __builtin_amdgcn_rcpf(lv[r]);
        #pragma unroll
        for (int ds = 0; ds < 4; ds++)
            #pragma unroll
            for (int r = 0; r < 4; r++) {
                int tq = q0 + qt * 16 + lq * 4 + r;
                float v = o[qt][ds][r] * li[r];
                ctx[((size_t)(b * 2048) + tq) * 1024 + h * 64 + ds * 16 + lr] = f2bf(v);
            }
    }
}

// ---------- host ----------
extern "C" void kernel_launch(void* const* d_in, const int* in_sizes, int n_in,
                              void* d_out, int out_size, void* d_ws, size_t ws_size,
                              hipStream_t stream) {
    (void)in_sizes; (void)n_in; (void)out_size; (void)ws_size;
    const float* x     = (const float*)d_in[0];
    const float* ln1   = (const float*)d_in[1];
    const float* alnw  = (const float*)d_in[2];
    const float* qkv_a = (const float*)d_in[3];
    const float* q_b   = (const float*)d_in[4];
    const float* kv_b  = (const float*)d_in[5];
    const float* o_a   = (const float*)d_in[6];
    const float* o_b   = (const float*)d_in[7];
    const float* ln2   = (const float*)d_in[8];
    const float* in_a  = (const float*)d_in[9];
    const float* in_b  = (const float*)d_in[10];
    const float* out_a = (const float*)d_in[11];
    const float* out_b = (const float*)d_in[12];
    const float* cosb  = (const float*)d_in[13];
    const float* sinb  = (const float*)d_in[14];
    float* out = (float*)d_out;
    char* ws = (char*)d_ws;

    // ---- weights bf16 [0, 15728640) ----
    u16* wqkv = (u16*)ws;              // 768x1024
    u16* wq   = wqkv + 786432;         // 1024x512
    u16* wkv  = wq   + 524288;         // 2048x256
    u16* wob  = wkv  + 524288;         // 1024x512 (o_b^T)
    u16* wia  = wob  + 524288;         // 384x1024
    u16* wib  = wia  + 393216;         // 4096x384
    u16* woa2 = wib  + 1572864;        // 384x4096 (out_a^T)
    u16* wob2 = woa2 + 1572864;        // 1024x384
    u16* woan = wob2 + 393216;         // 1024x512 (o_a cast)
    u16* woab = woan + 524288;         // 1024x1024 fused (o_a@o_b)^T

    // ---- activations, base G = ws + 15728640 ----
    char* G = ws + 15728640;
    u16*  hbuf  = (u16*)(G + 0);              // 16.8 MB [rms1 -> qkv]
    float* lat_raw = (float*)(G + 16777216);  // 25.2 MB [qkv -> rms768]
    u16*  lat   = (u16*)(G + 41943040);       // 12.6 MB [rms768 -> q,kv]
    u16*  qbuf  = (u16*)(G + 54525952);       // 16.8 MB [q -> rope]
    u16*  kvbuf = (u16*)(G + 71303168);       // 33.6 MB [kv -> rope,vtrans]
    u16*  q_r   = (u16*)(G + 0);              // reuse hbuf      [rope -> attn]
    u16*  k_r   = (u16*)(G + 16777216);       // reuse lat_raw   [rope -> attn]
    u16*  v_t   = (u16*)(G + 33554432);       // lat_raw tail+lat [vtrans -> attn]
    u16*  ctx   = (u16*)(G + 54525952);       // reuse qbuf      [attn -> o-gemm]
    float* x2   = (float*)(G + 0);            // 33.6 MB, reuse q_r/k_r [o -> final]
    u16*  h2    = (u16*)(G + 33554432);       // reuse v_t       [rms2 -> in_a]
    u16*  t1    = (u16*)(G + 50331648);       // 6.3 MB          [in_a -> in_b]
    u16*  t2    = (u16*)(G + 56623104);       // 64 MB           [in_b -> out_a]
    u16*  t3    = (u16*)(G + 50331648);       // reuse t1        [out_a -> out_b]

    TPack tp;
    tp.t[0] = { qkv_a, wqkv, 1024, 768,  0 };
    tp.t[1] = { q_b,   wq,   512,  1024, 768 };
    tp.t[2] = { kv_b,  wkv,  256,  2048, 1280 };
    tp.t[3] = { o_b,   wob,  512,  1024, 1792 };
    tp.t[4] = { in_a,  wia,  1024, 384,  2304 };
    tp.t[5] = { in_b,  wib,  384,  4096, 2688 };
    tp.t[6] = { out_a, woa2, 4096, 384,  4224 };
    tp.t[7] = { out_b, wob2, 384,  1024, 5760 };
    k_transpose_all<<<6144, dim3(32, 8), 0, stream>>>(tp);
    k_cvt<<<512, 256, 0, stream>>>(o_a, woan);
    // fused o-weight: W^T = o_b^T @ o_a  (bf16), [1024][1024]
    k_gemm64<1><<<dim3(16, 16), 256, 0, stream>>>(wob, 512, woan, 512, 1024, 1024, 512, nullptr, woab);

    k_rmsnorm<1024><<<NTOK, 256, 0, stream>>>(x, ln1, hbuf);
    k_gemm64<0><<<dim3(12, 128), 256, 0, stream>>>(hbuf, 1024, wqkv, 1024, NTOK, 768, 1024, lat_raw, nullptr);
    k_rmsnorm<768><<<NTOK, 256, 0, stream>>>(lat_raw, alnw, lat);
    k_gemm<1><<<dim3(8, 64),  256, 0, stream>>>(lat,       768, wq,  512, NTOK, 1024, 512, nullptr, qbuf,  nullptr);
    k_gemm<1><<<dim3(16, 64), 256, 0, stream>>>(lat + 512, 768, wkv, 256, NTOK, 2048, 256, nullptr, kvbuf, nullptr);
    k_rope<<<4096, 256, 0, stream>>>(qbuf, kvbuf, cosb, sinb, q_r, k_r);
    k_vtrans<<<dim3(32, 64), 256, 0, stream>>>(kvbuf, v_t);
    k_attn<<<1024, 256, 0, stream>>>(q_r, k_r, v_t, ctx);
    // attn_out + residual in one GEMM via fused weight
    k_gemm<3><<<dim3(8, 64), 256, 0, stream>>>(ctx, 1024, woab, 1024, NTOK, 1024, 1024, x2, nullptr, x);
    k_rmsnorm<1024><<<NTOK, 256, 0, stream>>>(x2, ln2, h2);
    k_gemm64<1><<<dim3(6, 128), 256, 0, stream>>>(h2, 1024, wia, 1024, NTOK, 384, 1024, nullptr, t1);
    k_gemm<2><<<dim3(32, 64), 256, 0, stream>>>(t1, 384, wib, 384, NTOK, 4096, 384, nullptr, t2, nullptr);
    k_gemm64<1><<<dim3(6, 128), 256, 0, stream>>>(t2, 4096, woa2, 4096, NTOK, 384, 4096, nullptr, t3);
    k_gemm<3><<<dim3(8, 64), 256, 0, stream>>>(t3, 384, wob2, 384, NTOK, 1024, 384, out, nullptr, x2);
}

// Round 13
// 451.530 us; speedup vs baseline: 1.1138x; 1.0349x over previous
//
#include <hip/hip_runtime.h>
#include <hip/hip_bf16.h>
#include <stdint.h>

// ---------- problem constants ----------
#define NTOK 8192   // B*T

typedef unsigned short u16;
typedef __attribute__((ext_vector_type(4))) float f32x4;
typedef __attribute__((ext_vector_type(8))) short s16x8;
typedef __attribute__((ext_vector_type(4))) short s16x4;
typedef __attribute__((ext_vector_type(8))) u16   u16x8;
typedef __attribute__((ext_vector_type(4))) u16   u16x4;
typedef __attribute__((ext_vector_type(4))) uint32_t u32x4;

__device__ __forceinline__ float fast_exp2(float x) {
    return __builtin_amdgcn_exp2f(x);
}
__device__ __forceinline__ u16 f2bf(float f) {
    uint32_t u = __float_as_uint(f);
    u = (u + 0x7FFFu + ((u >> 16) & 1u)) >> 16;   // RNE
    return (u16)u;
}
__device__ __forceinline__ float bf2f(u16 h) {
    return __uint_as_float(((uint32_t)h) << 16);
}
__device__ __forceinline__ void async_cp16(const void* g, void* l) {
    __builtin_amdgcn_global_load_lds(
        (const __attribute__((address_space(1))) void*)g,
        (__attribute__((address_space(3))) void*)l, 16, 0, 0);
}
__device__ __forceinline__ void wait_vm4()   { asm volatile("s_waitcnt vmcnt(4)" ::: "memory"); }
__device__ __forceinline__ void wait_vm0()   { asm volatile("s_waitcnt vmcnt(0)" ::: "memory"); }
__device__ __forceinline__ void wait_lgkm0() { asm volatile("s_waitcnt lgkmcnt(0)" ::: "memory"); }
__device__ __forceinline__ void raw_barrier(){ asm volatile("s_barrier" ::: "memory"); }

// XCD-aware tile remap (T1): dispatch order round-robins XCDs; give XCD k a
// CONTIGUOUS chunk of work tiles so same-XCD blocks share A-panels in its L2.
// Requires nwg % 8 == 0 (true for every grid below).
// r8 A/B: +45us total. r9/r11 tile sweep: skinny GEMMs are occupancy-bound
// (64^2 @6 blk/CU = 465 < 128x64 @3 = 489 < 128^2 @1.5 = 503) -> keep 64^2.
__device__ __forceinline__ void xcd_tile(int& bx, int& by) {
    int gx = gridDim.x;
    int nwg = gx * gridDim.y;
    int flat = blockIdx.y * gx + blockIdx.x;
    int swz = (flat & 7) * (nwg >> 3) + (flat >> 3);
    bx = swz % gx;
    by = swz / gx;
}

// ---------- all weight transposes in one launch: f32 [K][N] -> bf16 [N][K] ----------
struct TDesc { const float* s; u16* d; int K; int N; int tile0; };
struct TPack { TDesc t[8]; };

__global__ __launch_bounds__(256) void k_transpose_all(TPack p)
{
    __shared__ float tile[32][33];
    int bid = blockIdx.x;
    int i = 0;
    #pragma unroll
    for (int j = 1; j < 8; j++) if (bid >= p.t[j].tile0) i = j;
    const float* src = p.t[i].s;
    u16* dst = p.t[i].d;
    int K = p.t[i].K, N = p.t[i].N;
    int local = bid - p.t[i].tile0;
    int nx = N >> 5;
    int n0 = (local % nx) * 32, k0 = (local / nx) * 32;
    int tx = threadIdx.x, ty = threadIdx.y;      // block (32,8)
    #pragma unroll
    for (int r = 0; r < 32; r += 8)
        tile[ty + r][tx] = src[(size_t)(k0 + ty + r) * N + n0 + tx];
    __syncthreads();
    #pragma unroll
    for (int r = 0; r < 32; r += 8)
        dst[(size_t)(n0 + ty + r) * K + k0 + tx] = f2bf(tile[tx][ty + r]);
}

// ---------- f32 -> bf16 flat convert ----------
__global__ __launch_bounds__(256) void k_cvt(
    const float* __restrict__ in, u16* __restrict__ out)
{
    int i = (blockIdx.x * 256 + threadIdx.x) * 4;
    f32x4 v = *(const f32x4*)&in[i];
    u16x4 o;
    #pragma unroll
    for (int j = 0; j < 4; j++) o[j] = f2bf(v[j]);
    *(u16x4*)&out[i] = o;
}

// ---------- RMSNorm: f32 in, bf16 out ----------
template<int W>
__global__ __launch_bounds__(256) void k_rmsnorm(
    const float* __restrict__ x, const float* __restrict__ w, u16* __restrict__ out)
{
    constexpr int E = W / 256;
    int row = blockIdx.x, tid = threadIdx.x;
    const float* xr = x + (size_t)row * W;
    float v[E]; float ss = 0.f;
    #pragma unroll
    for (int i = 0; i < E; i++) { v[i] = xr[tid + i * 256]; ss += v[i] * v[i]; }
    #pragma unroll
    for (int m = 1; m < 64; m <<= 1) ss += __shfl_xor(ss, m, 64);
    __shared__ float red[4];
    if ((tid & 63) == 0) red[tid >> 6] = ss;
    __syncthreads();
    ss = red[0] + red[1] + red[2] + red[3];
    float scale = rsqrtf(ss / (float)W + 1e-6f);
    u16* orow = out + (size_t)row * W;
    #pragma unroll
    for (int i = 0; i < E; i++)
        orow[tid + i * 256] = f2bf(w[tid + i * 256] * (v[i] * scale));
}

// ---------- GEMM 128x128 tile, double-buffered pipelined K-loop ----------
// EPI: 0 = f32 store; 1 = bf16 store; 2 = gelu+bf16; 3 = f32 + resid
//      4 = fused RoPE-Q -> q_r [B,H,T,64] (x QS); tile 128 = 2 heads, wave
//          quadrant wn = one head; rotate-pair (d,d+16) = acc[ms][ns]/[ns+1]
//          of the SAME thread -> zero cross-lane.
//      5 = fused RoPE-K + V-transpose: wn=0 waves rope K -> k_r; wn=1 waves
//          stage V-half through dead As/Bs LDS, barrier, coalesced u16x8
//          stores along t -> v_t [B,H,64,T]. (k_rope + k_vtrans eliminated.)
template<int EPI>
__global__ __launch_bounds__(256) void k_gemm(
    const u16* __restrict__ A, int lda,
    const u16* __restrict__ Bt, int ldb,
    int M, int N, int K,
    float* __restrict__ outF, u16* __restrict__ outB,
    const float* __restrict__ resid,
    const float* __restrict__ cosP, const float* __restrict__ sinP,
    u16* __restrict__ outB2)
{
    __shared__ __align__(16) u16 As[2][4096];
    __shared__ __align__(16) u16 Bs[2][4096];
    int tid = threadIdx.x;
    int w = tid >> 6, lane = tid & 63;
    int bx, by; xcd_tile(bx, by);
    int m0 = by * 128, n0 = bx * 128;
    int wm = w & 1, wn = w >> 1;
    int lr = lane & 15, lq = lane >> 4;

    f32x4 acc[4][4];
    #pragma unroll
    for (int i = 0; i < 4; i++)
        #pragma unroll
        for (int j = 0; j < 4; j++) acc[i][j] = (f32x4)(0.f);

    int ar = tid >> 2;
    int ac = (tid & 3) * 8;
    const u16* Ag = A  + (size_t)(m0 + ar) * lda + ac;
    const u16* Bg = Bt + (size_t)(n0 + ar) * ldb + ac;
    int lo = w * 512;

    auto stage = [&](int kt, int s) {
        const u16* a  = Ag + kt * 32;
        const u16* bp = Bg + kt * 32;
        async_cp16(a,                     &As[s][lo]);
        async_cp16(a + (size_t)64 * lda,  &As[s][lo + 2048]);
        async_cp16(bp,                    &Bs[s][lo]);
        async_cp16(bp + (size_t)64 * ldb, &Bs[s][lo + 2048]);
    };

    int nk = K >> 5;
    stage(0, 0);
    stage(1, 1);
    for (int k = 0; k < nk; k++) {
        if (k + 1 < nk) wait_vm4(); else wait_vm0();
        raw_barrier();
        int s = k & 1;
        s16x8 af[4], bfr[4];
        #pragma unroll
        for (int ms = 0; ms < 4; ms++)
            af[ms] = *reinterpret_cast<const s16x8*>(&As[s][(wm * 64 + ms * 16 + lr) * 32 + lq * 8]);
        #pragma unroll
        for (int ns = 0; ns < 4; ns++)
            bfr[ns] = *reinterpret_cast<const s16x8*>(&Bs[s][(wn * 64 + ns * 16 + lr) * 32 + lq * 8]);
        #pragma unroll
        for (int ms = 0; ms < 4; ms++)
            #pragma unroll
            for (int ns = 0; ns < 4; ns++)
                acc[ms][ns] = __builtin_amdgcn_mfma_f32_16x16x32_bf16(af[ms], bfr[ns], acc[ms][ns], 0, 0, 0);
        wait_lgkm0();
        raw_barrier();
        if (k + 2 < nk) stage(k + 2, s);
    }

    if constexpr (EPI <= 3) {
        #pragma unroll
        for (int ms = 0; ms < 4; ms++) {
            #pragma unroll
            for (int ns = 0; ns < 4; ns++) {
                int col = n0 + wn * 64 + ns * 16 + lr;
                #pragma unroll
                for (int r = 0; r < 4; r++) {
                    int row = m0 + wm * 64 + ms * 16 + lq * 4 + r;
                    float v = acc[ms][ns][r];
                    size_t idx = (size_t)row * N + col;
                    if (EPI == 0) {
                        outF[idx] = v;
                    } else if (EPI == 1) {
                        outB[idx] = f2bf(v);
                    } else if (EPI == 2) {
                        // gelu(tanh) via exp2+rcp: 0.5v(1+tanh t) = v - v/(1+e^{2t})
                        float t = 0.7978845608028654f * (v + 0.044715f * v * v * v);
                        float e = fast_exp2(t * 2.8853900817779268f);
                        outB[idx] = f2bf(v - v * __builtin_amdgcn_rcpf(1.f + e));
                    } else {
                        outF[idx] = v + resid[idx];
                    }
                }
            }
        }
    } else if constexpr (EPI == 4) {
        // fused RoPE-Q: q_r[((b*16+h)*2048+t)*64 + d], scaled by QS
        const float QS = 0.125f * 1.4426950408889634f;
        int h = (n0 >> 6) + wn;
        #pragma unroll
        for (int ms = 0; ms < 4; ms++) {
            #pragma unroll
            for (int r = 0; r < 4; r++) {
                int row = m0 + wm * 64 + ms * 16 + lq * 4 + r;
                int b = row >> 11, t = row & 2047;
                u16* dst = outB + ((size_t)(b * 16 + h) * 2048 + t) * 64;
                float x0 = acc[ms][0][r], x1 = acc[ms][1][r];
                float c0 = cosP[t * 32 + lr],      s0 = sinP[t * 32 + lr];
                float c1 = cosP[t * 32 + 16 + lr], s1 = sinP[t * 32 + 16 + lr];
                dst[lr]      = f2bf((x0 * c0 - x1 * s0) * QS);
                dst[16 + lr] = f2bf((x1 * c1 + x0 * s1) * QS);
                dst[32 + lr] = f2bf(acc[ms][2][r] * QS);
                dst[48 + lr] = f2bf(acc[ms][3][r] * QS);
            }
        }
    } else {
        // EPI == 5: tile 128 = one head (K-half cols 0-63, V-half 64-127)
        int h  = n0 >> 7;
        int b  = m0 >> 11;
        int t0 = m0 & 2047;
        if (wn == 0) {
            // K-half: rope (no scale) -> k_r
            #pragma unroll
            for (int ms = 0; ms < 4; ms++) {
                #pragma unroll
                for (int r = 0; r < 4; r++) {
                    int row = m0 + wm * 64 + ms * 16 + lq * 4 + r;
                    int t = row & 2047;
                    u16* dst = outB + ((size_t)(b * 16 + h) * 2048 + t) * 64;
                    float x0 = acc[ms][0][r], x1 = acc[ms][1][r];
                    float c0 = cosP[t * 32 + lr],      s0 = sinP[t * 32 + lr];
                    float c1 = cosP[t * 32 + 16 + lr], s1 = sinP[t * 32 + 16 + lr];
                    dst[lr]      = f2bf(x0 * c0 - x1 * s0);
                    dst[16 + lr] = f2bf(x1 * c1 + x0 * s1);
                    dst[32 + lr] = f2bf(acc[ms][2][r]);
                    dst[48 + lr] = f2bf(acc[ms][3][r]);
                }
            }
        } else {
            // V-half: stage [64 rows][68 ld] into the (dead) As/Bs buffers;
            // wm=0 rows 0-63 -> As, wm=1 rows 64-127 -> Bs (4352 u16 <= 8192).
            u16* vb = wm ? (u16*)Bs : (u16*)As;
            #pragma unroll
            for (int ms = 0; ms < 4; ms++)
                #pragma unroll
                for (int ns = 0; ns < 4; ns++)
                    #pragma unroll
                    for (int r = 0; r < 4; r++)
                        vb[(ms * 16 + lq * 4 + r) * 68 + ns * 16 + lr] =
                            f2bf(acc[ms][ns][r]);
        }
        raw_barrier();      // all 4 waves; LDS writes visible
        if (wn == 1) {
            // 128 threads: dv = idx>>1 (0..63), th = (idx&1)*64
            int idxv = (w - 2) * 64 + lane;
            int dv = idxv >> 1;
            int th = (idxv & 1) * 64;
            const u16* rb = th ? (const u16*)Bs : (const u16*)As;
            u16* dst = outB2 + ((size_t)(b * 16 + h) * 64 + dv) * 2048 + t0 + th;
            #pragma unroll
            for (int j0 = 0; j0 < 64; j0 += 8) {
                u16x8 vv;
                #pragma unroll
                for (int j = 0; j < 8; j++) vv[j] = rb[(j0 + j) * 68 + dv];
                *(u16x8*)&dst[j0] = vv;
            }
        }
    }
}

// ---------- GEMM 64x64 tile (skinny-N, occupancy-bound shapes) ----------
template<int EPI>
__global__ __launch_bounds__(256) void k_gemm64(
    const u16* __restrict__ A, int lda,
    const u16* __restrict__ Bt, int ldb,
    int M, int N, int K,
    float* __restrict__ outF, u16* __restrict__ outB)
{
    __shared__ __align__(16) u16 As[2][4096];   // [kc2][64 rows][32 u16]
    __shared__ __align__(16) u16 Bs[2][4096];
    int tid = threadIdx.x;
    int w = tid >> 6, lane = tid & 63;
    int bx, by; xcd_tile(bx, by);
    int m0 = by * 64, n0 = bx * 64;
    int wm = w & 1, wn = w >> 1;
    int lr = lane & 15, lq = lane >> 4;

    f32x4 acc[2][2];
    #pragma unroll
    for (int i = 0; i < 2; i++)
        #pragma unroll
        for (int j = 0; j < 2; j++) acc[i][j] = (f32x4)(0.f);

    int srow = tid >> 2;            // 0..63
    int sq   = tid & 3;             // 16B quarter within 32-u16 chunk
    const u16* Ag = A  + (size_t)(m0 + srow) * lda + sq * 8;
    const u16* Bg = Bt + (size_t)(n0 + srow) * ldb + sq * 8;
    int lo = srow * 32 + sq * 8;

    auto stage = [&](int kt, int s) {
        const u16* a  = Ag + kt * 64;
        const u16* bp = Bg + kt * 64;
        async_cp16(a,       &As[s][lo]);
        async_cp16(a + 32,  &As[s][2048 + lo]);
        async_cp16(bp,      &Bs[s][lo]);
        async_cp16(bp + 32, &Bs[s][2048 + lo]);
    };

    int nk = K >> 6;
    stage(0, 0);
    stage(1, 1);
    for (int k = 0; k < nk; k++) {
        if (k + 1 < nk) wait_vm4(); else wait_vm0();
        raw_barrier();
        int s = k & 1;
        s16x8 af[2][2], bfr[2][2];
        #pragma unroll
        for (int kc = 0; kc < 2; kc++) {
            #pragma unroll
            for (int ms = 0; ms < 2; ms++)
                af[ms][kc] = *reinterpret_cast<const s16x8*>(
                    &As[s][kc * 2048 + (wm * 32 + ms * 16 + lr) * 32 + lq * 8]);
            #pragma unroll
            for (int ns = 0; ns < 2; ns++)
                bfr[ns][kc] = *reinterpret_cast<const s16x8*>(
                    &Bs[s][kc * 2048 + (wn * 32 + ns * 16 + lr) * 32 + lq * 8]);
        }
        #pragma unroll
        for (int kc = 0; kc < 2; kc++)
            #pragma unroll
            for (int ms = 0; ms < 2; ms++)
                #pragma unroll
                for (int ns = 0; ns < 2; ns++)
                    acc[ms][ns] = __builtin_amdgcn_mfma_f32_16x16x32_bf16(
                        af[ms][kc], bfr[ns][kc], acc[ms][ns], 0, 0, 0);
        wait_lgkm0();
        raw_barrier();
        if (k + 2 < nk) stage(k + 2, s);
    }

    #pragma unroll
    for (int ms = 0; ms < 2; ms++) {
        #pragma unroll
        for (int ns = 0; ns < 2; ns++) {
            int col = n0 + wn * 32 + ns * 16 + lr;
            #pragma unroll
            for (int r = 0; r < 4; r++) {
                int row = m0 + wm * 32 + ms * 16 + lq * 4 + r;
                float v = acc[ms][ns][r];
                size_t idx = (size_t)row * N + col;
                if (EPI == 0) outF[idx] = v;
                else          outB[idx] = f2bf(v);
            }
        }
    }
}

// ---------- flash attention v9 (verified 97us) ----------
// Keeps: XCD-partition remap (FETCH 139->41MB), pinned-zero C-operand, ones-MFMA
// row-sum, cvt_pk packing, 2-bit swizzle + dual ds_read_b64 V path,
// advancing-pointer staging, literal-offset 2x unroll, setprio, v_rcp epilogue.
// LDS analysis (r7): conflict-free; SQ_LDS_BANK_CONFLICT=2^23 is inherent
// multi-phase cycles of wide reads. Parked.
__global__ __launch_bounds__(256) void k_attn(
    const u16* __restrict__ q_r, const u16* __restrict__ k_r,
    const u16* __restrict__ v_t, u16* __restrict__ ctx)
{
    __shared__ __align__(16) u16 Ks[2][4096];
    __shared__ __align__(16) u16 Vs[2][4096];
    int tid = threadIdx.x, w = tid >> 6, lane = tid & 63;
    // XCD-partition remap (8 XCDs, grid 1024 = 8 xcd * 8 bh * 16 xb)
    int flat = blockIdx.x;
    int xcd = flat & 7;
    int idx = flat >> 3;
    int bh  = xcd * 8 + (idx & 7);
    int xb  = idx >> 3;                         // 0..15
    int b = bh >> 4, h = bh & 15;
    int q0 = xb * 128 + w * 32;
    const u16* Qp = q_r + (size_t)bh * 2048 * 64;
    const u16* Kp = k_r + (size_t)bh * 2048 * 64;
    const u16* Vp = v_t + (size_t)bh * 64 * 2048;
    int lr = lane & 15, lq = lane >> 4;
    int swz = (lr >> 1) & 3;                    // 2-bit read-side chunk16 XOR

    s16x8 qf[2][2];
    #pragma unroll
    for (int qc = 0; qc < 2; qc++)
        #pragma unroll
        for (int kf = 0; kf < 2; kf++)
            qf[qc][kf] = *(const s16x8*)&Qp[(size_t)(q0 + qc * 16 + lr) * 64 + kf * 32 + lq * 8];

    // bf16 1.0 fragment for the ones-MFMA row-sum
    s16x8 ones;
    #pragma unroll
    for (int j = 0; j < 8; j++) ones[j] = (short)0x3F80;

    // pinned zero quad for QK accumulator C-operand
    f32x4 fz = (f32x4)(0.f);
    asm("" : "+v"(fz));

    // staging: pre-swizzled global source, linear LDS dest (2-bit swizzle).
    int schunk = ((lane & 3) ^ ((lane >> 3) & 3)) * 8;
    const u16* gp;
    u16 *lp0, *lp1;
    size_t grow;
    int gAdv;
    if (w < 2) {
        gp = Kp + (size_t)(lane >> 2) * 64 + w * 32 + schunk;
        lp0 = &Ks[0][w * 2048]; lp1 = &Ks[1][w * 2048];
        grow = 16 * 64;  gAdv = 64 * 64;
    } else {
        gp = Vp + (size_t)(lane >> 2) * 2048 + (w - 2) * 32 + schunk;
        lp0 = &Vs[0][(w - 2) * 2048]; lp1 = &Vs[1][(w - 2) * 2048];
        grow = 16 * 2048; gAdv = 64;
    }
    auto stageP = [&](u16* lp) {
        #pragma unroll
        for (int g = 0; g < 4; g++)
            async_cp16(gp + g * grow, lp + g * 512);
        gp += gAdv;
    };

    f32x4 o[2][4];
    #pragma unroll
    for (int qt = 0; qt < 2; qt++)
        #pragma unroll
        for (int ds = 0; ds < 4; ds++) o[qt][ds] = (f32x4)(0.f);
    f32x4 lacc0 = (f32x4)(0.f), lacc1 = (f32x4)(0.f);

#define ATTN_BODY(S)                                                           \
  {                                                                            \
    f32x4 sc[2][4];                                                            \
    __builtin_amdgcn_s_setprio(1);                                             \
    _Pragma("unroll")                                                          \
    for (int ns = 0; ns < 4; ns++) {                                           \
      int ko = (ns * 16 + lr) * 32 + ((lq ^ swz) * 8);                         \
      s16x8 a0 = *(const s16x8*)&Ks[S][ko];                                    \
      s16x8 a1 = *(const s16x8*)&Ks[S][2048 + ko];                             \
      _Pragma("unroll")                                                        \
      for (int qc = 0; qc < 2; qc++) {                                         \
        f32x4 t;                                                               \
        t = __builtin_amdgcn_mfma_f32_16x16x32_bf16(a0, qf[qc][0], fz, 0, 0, 0);\
        t = __builtin_amdgcn_mfma_f32_16x16x32_bf16(a1, qf[qc][1], t, 0, 0, 0);\
        sc[qc][ns] = t;                                                        \
      }                                                                        \
    }                                                                          \
    __builtin_amdgcn_s_setprio(0);                                             \
    _Pragma("unroll")                                                          \
    for (int kf = 0; kf < 2; kf++) {                                           \
      u32x4 w0, w1;                                                            \
      _Pragma("unroll")                                                        \
      for (int j = 0; j < 4; j++) {                                            \
        int ns = kf * 2 + (j >> 1);                                            \
        int r0 = (j & 1) * 2;                                                  \
        float ea = fast_exp2(sc[0][ns][r0]);                                   \
        float eb = fast_exp2(sc[0][ns][r0 + 1]);                               \
        float ec = fast_exp2(sc[1][ns][r0]);                                   \
        float ed = fast_exp2(sc[1][ns][r0 + 1]);                               \
        uint32_t t0, t1;                                                       \
        asm("v_cvt_pk_bf16_f32 %0, %1, %2" : "=v"(t0) : "v"(ea), "v"(eb));     \
        asm("v_cvt_pk_bf16_f32 %0, %1, %2" : "=v"(t1) : "v"(ec), "v"(ed));     \
        w0[j] = t0; w1[j] = t1;                                                \
      }                                                                        \
      s16x8 pk0 = __builtin_bit_cast(s16x8, w0);                               \
      s16x8 pk1 = __builtin_bit_cast(s16x8, w1);                               \
      __builtin_amdgcn_s_setprio(1);                                           \
      lacc0 = __builtin_amdgcn_mfma_f32_16x16x32_bf16(pk0, ones, lacc0, 0,0,0);\
      lacc1 = __builtin_amdgcn_mfma_f32_16x16x32_bf16(pk1, ones, lacc1, 0,0,0);\
      _Pragma("unroll")                                                        \
      for (int ds = 0; ds < 4; ds++) {                                         \
        int vbase = kf * 2048 + (ds * 16 + lr) * 32 + (lq & 1) * 4;            \
        s16x4 vlo = *(const s16x4*)&Vs[S][vbase + (((lq >> 1)    ) ^ swz) * 8];\
        s16x4 vhi = *(const s16x4*)&Vs[S][vbase + (((lq >> 1) | 2) ^ swz) * 8];\
        s16x8 vf = __builtin_shufflevector(vlo, vhi, 0, 1, 2, 3, 4, 5, 6, 7);  \
        o[0][ds] = __builtin_amdgcn_mfma_f32_16x16x32_bf16(pk0, vf, o[0][ds], 0, 0, 0);\
        o[1][ds] = __builtin_amdgcn_mfma_f32_16x16x32_bf16(pk1, vf, o[1][ds], 0, 0, 0);\
      }                                                                        \
      __builtin_amdgcn_s_setprio(0);                                           \
    }                                                                          \
  }

    stageP(lp0);   // tile 0 -> buf0
    stageP(lp1);   // tile 1 -> buf1
    for (int k2 = 0; k2 < 15; k2++) {
        wait_vm4(); raw_barrier();
        ATTN_BODY(0)
        wait_lgkm0(); raw_barrier();
        stageP(lp0);
        wait_vm4(); raw_barrier();
        ATTN_BODY(1)
        wait_lgkm0(); raw_barrier();
        stageP(lp1);
    }
    wait_vm4(); raw_barrier();
    ATTN_BODY(0)
    wait_vm0(); raw_barrier();
    ATTN_BODY(1)
#undef ATTN_BODY

    #pragma unroll
    for (int qt = 0; qt < 2; qt++) {
        f32x4 lv = qt ? lacc1 : lacc0;
        float li[4];
        #pragma unroll
        for (int r = 0; r < 4; r++) li[r] = __builtin_amdgcn_rcpf(lv[r]);
        #pragma unroll
        for (int ds = 0; ds < 4; ds++)
            #pragma unroll
            for (int r = 0; r < 4; r++) {
                int tq = q0 + qt * 16 + lq * 4 + r;
                float v = o[qt][ds][r] * li[r];
                ctx[((size_t)(b * 2048) + tq) * 1024 + h * 64 + ds * 16 + lr] = f2bf(v);
            }
    }
}

// ---------- host ----------
extern "C" void kernel_launch(void* const* d_in, const int* in_sizes, int n_in,
                              void* d_out, int out_size, void* d_ws, size_t ws_size,
                              hipStream_t stream) {
    (void)in_sizes; (void)n_in; (void)out_size; (void)ws_size;
    const float* x     = (const float*)d_in[0];
    const float* ln1   = (const float*)d_in[1];
    const float* alnw  = (const float*)d_in[2];
    const float* qkv_a = (const float*)d_in[3];
    const float* q_b   = (const float*)d_in[4];
    const float* kv_b  = (const float*)d_in[5];
    const float* o_a   = (const float*)d_in[6];
    const float* o_b   = (const float*)d_in[7];
    const float* ln2   = (const float*)d_in[8];
    const float* in_a  = (const float*)d_in[9];
    const float* in_b  = (const float*)d_in[10];
    const float* out_a = (const float*)d_in[11];
    const float* out_b = (const float*)d_in[12];
    const float* cosb  = (const float*)d_in[13];
    const float* sinb  = (const float*)d_in[14];
    float* out = (float*)d_out;
    char* ws = (char*)d_ws;

    // ---- weights bf16 [0, 15728640) ----
    u16* wqkv = (u16*)ws;              // 768x1024
    u16* wq   = wqkv + 786432;         // 1024x512
    u16* wkv  = wq   + 524288;         // 2048x256
    u16* wob  = wkv  + 524288;         // 1024x512 (o_b^T)
    u16* wia  = wob  + 524288;         // 384x1024
    u16* wib  = wia  + 393216;         // 4096x384
    u16* woa2 = wib  + 1572864;        // 384x4096 (out_a^T)
    u16* wob2 = woa2 + 1572864;        // 1024x384
    u16* woan = wob2 + 393216;         // 1024x512 (o_a cast)
    u16* woab = woan + 524288;         // 1024x1024 fused (o_a@o_b)^T

    // ---- activations, base G = ws + 15728640 ----
    char* G = ws + 15728640;
    u16*  hbuf  = (u16*)(G + 0);              // 16.8 MB [rms1 -> qkv]
    float* lat_raw = (float*)(G + 16777216);  // 25.2 MB [qkv -> rms768]
    u16*  lat   = (u16*)(G + 41943040);       // 12.6 MB [rms768 -> q,kv]
    u16*  q_r   = (u16*)(G + 0);              // reuse hbuf      [q-gemm(rope) -> attn]
    u16*  k_r   = (u16*)(G + 16777216);       // reuse lat_raw   [kv-gemm(rope) -> attn]
    u16*  v_t   = (u16*)(G + 71303168);       // old kvbuf slot  [kv-gemm(vtrans) -> attn]
                                              // (moved: old slot overlapped lat, which
                                              //  the fused kv-gemm reads as A)
    u16*  ctx   = (u16*)(G + 54525952);       // [attn -> o-gemm]
    float* x2   = (float*)(G + 0);            // 33.6 MB, reuse q_r/k_r [o -> final]
    u16*  h2    = (u16*)(G + 33554432);       // [rms2 -> in_a]
    u16*  t1    = (u16*)(G + 50331648);       // 6.3 MB          [in_a -> in_b]
    u16*  t2    = (u16*)(G + 56623104);       // 64 MB           [in_b -> out_a]
    u16*  t3    = (u16*)(G + 50331648);       // reuse t1        [out_a -> out_b]

    TPack tp;
    tp.t[0] = { qkv_a, wqkv, 1024, 768,  0 };
    tp.t[1] = { q_b,   wq,   512,  1024, 768 };
    tp.t[2] = { kv_b,  wkv,  256,  2048, 1280 };
    tp.t[3] = { o_b,   wob,  512,  1024, 1792 };
    tp.t[4] = { in_a,  wia,  1024, 384,  2304 };
    tp.t[5] = { in_b,  wib,  384,  4096, 2688 };
    tp.t[6] = { out_a, woa2, 4096, 384,  4224 };
    tp.t[7] = { out_b, wob2, 384,  1024, 5760 };
    k_transpose_all<<<6144, dim3(32, 8), 0, stream>>>(tp);
    k_cvt<<<512, 256, 0, stream>>>(o_a, woan);
    // fused o-weight: W^T = o_b^T @ o_a  (bf16), [1024][1024]
    k_gemm64<1><<<dim3(16, 16), 256, 0, stream>>>(wob, 512, woan, 512, 1024, 1024, 512, nullptr, woab);

    k_rmsnorm<1024><<<NTOK, 256, 0, stream>>>(x, ln1, hbuf);
    k_gemm64<0><<<dim3(12, 128), 256, 0, stream>>>(hbuf, 1024, wqkv, 1024, NTOK, 768, 1024, lat_raw, nullptr);
    k_rmsnorm<768><<<NTOK, 256, 0, stream>>>(lat_raw, alnw, lat);
    // q-GEMM with fused RoPE -> q_r directly
    k_gemm<4><<<dim3(8, 64),  256, 0, stream>>>(lat,       768, wq,  512, NTOK, 1024, 512,
                                                nullptr, q_r, nullptr, cosb, sinb, nullptr);
    // kv-GEMM with fused RoPE-K -> k_r and V-transpose -> v_t
    k_gemm<5><<<dim3(16, 64), 256, 0, stream>>>(lat + 512, 768, wkv, 256, NTOK, 2048, 256,
                                                nullptr, k_r, nullptr, cosb, sinb, v_t);
    k_attn<<<1024, 256, 0, stream>>>(q_r, k_r, v_t, ctx);
    // attn_out + residual in one GEMM via fused weight
    k_gemm<3><<<dim3(8, 64), 256, 0, stream>>>(ctx, 1024, woab, 1024, NTOK, 1024, 1024,
                                               x2, nullptr, x, nullptr, nullptr, nullptr);
    k_rmsnorm<1024><<<NTOK, 256, 0, stream>>>(x2, ln2, h2);
    k_gemm64<1><<<dim3(6, 128), 256, 0, stream>>>(h2, 1024, wia, 1024, NTOK, 384, 1024, nullptr, t1);
    k_gemm<2><<<dim3(32, 64), 256, 0, stream>>>(t1, 384, wib, 384, NTOK, 4096, 384,
                                                nullptr, t2, nullptr, nullptr, nullptr, nullptr);
    k_gemm64<1><<<dim3(6, 128), 256, 0, stream>>>(t2, 4096, woa2, 4096, NTOK, 384, 4096, nullptr, t3);
    k_gemm<3><<<dim3(8, 64), 256, 0, stream>>>(t3, 384, wob2, 384, NTOK, 1024, 384,
                                               out, nullptr, x2, nullptr, nullptr, nullptr);
}